// Round 5
// baseline (1725.952 us; speedup 1.0000x reference)
//
#include <hip/hip_runtime.h>
#include <math.h>

#define K_     191
#define LD     192
#define N_     147456
#define MSUB   16
#define NT     15
#define TRI_N  18336   // 191*192/2
#define SMEM_SZ ((TRI_N + 192 + 192 + 1056) * 8)
// k_sub dynamic LDS: 6880 doubles + 32 ints + 18336 floats
#define SMEM2_SZ (6880 * 8 + 32 * 4 + TRI_N * 4)

// k_rr geometry: 64-wide col blocks, 6 pairs, 128 K-splits
#define NPAIR  6
#define NSPLIT 128
#define CHUNK  (N_ / NSPLIT)   // 1152
#define RSTEP  32

// db5 decomposition filters (pywt convention), f32 as in reference
__constant__ float c_lo[10] = {
  0.003335725285001549f, -0.012580751999015526f, -0.006241490213011705f,
  0.07757149384006515f,  -0.03224486958502952f, -0.24229488706619015f,
  0.13842814590110342f,   0.7243085284385744f,   0.6038292697974729f,
  0.160102397974125f };
__constant__ float c_hi[10] = {
  0.160102397974125f,    -0.6038292697974729f,   0.7243085284385744f,
 -0.13842814590110342f,  -0.24229488706619015f,  0.03224486958502952f,
  0.07757149384006515f,   0.006241490213011705f,-0.012580751999015526f,
 -0.003335725285001549f };

// ---------------- column sums of x (f64), for the regression mean ----------
__global__ __launch_bounds__(256) void k_colsum(const float* __restrict__ x,
                                                double* __restrict__ m)
{
  int t = threadIdx.x;
  long base = (long)blockIdx.x * 512;
  if (t < K_) {
    double s = 0.0;
    const float* p = x + base * K_ + t;
    for (int r = 0; r < 512; ++r) s += (double)p[(long)r * K_];
    atomicAdd(&m[t], s);
  }
}

// ---------------- rr = x^T x, register-tiled VALU f64, split-K atomics -----
__global__ __launch_bounds__(256, 3) void k_rr(const float* __restrict__ x,
                                               double* __restrict__ rrg)
{
  __shared__ double Asd[RSTEP][64];
  __shared__ double Bsd[RSTEP][64];

  const int bid   = blockIdx.x;
  const int split = bid & (NSPLIT - 1);
  const int pair  = bid >> 7;
  const int BI[6] = {0, 0, 0, 1, 1, 2};
  const int BJ[6] = {0, 1, 2, 1, 2, 2};
  const int bi = BI[pair], bj = BJ[pair];
  const int ca = bi * 64, cb = bj * 64;

  const int t  = threadIdx.x;
  const int tx = t & 15, ty = t >> 4;
  const long n0 = (long)split * CHUNK;

  double acc[4][4];
  #pragma unroll
  for (int v = 0; v < 4; ++v)
    #pragma unroll
    for (int u = 0; u < 4; ++u) acc[v][u] = 0.0;

  for (int r0 = 0; r0 < CHUNK; r0 += RSTEP) {
    for (int s = t; s < RSTEP * 16; s += 256) {
      int row = s >> 4, g = s & 15;
      long gr = (n0 + r0 + row) * (long)K_;
      int c4a = ca + g * 4, c4b = cb + g * 4;
      #pragma unroll
      for (int e = 0; e < 4; ++e) {
        Asd[row][g * 4 + e] = (c4a + e < K_) ? (double)x[gr + c4a + e] : 0.0;
        Bsd[row][g * 4 + e] = (c4b + e < K_) ? (double)x[gr + c4b + e] : 0.0;
      }
    }
    __syncthreads();
    #pragma unroll 4
    for (int k = 0; k < RSTEP; ++k) {
      double a0 = Asd[k][ty],      a1 = Asd[k][ty + 16];
      double a2 = Asd[k][ty + 32], a3 = Asd[k][ty + 48];
      double b0 = Bsd[k][tx],      b1 = Bsd[k][tx + 16];
      double b2 = Bsd[k][tx + 32], b3 = Bsd[k][tx + 48];
      acc[0][0] += a0 * b0; acc[0][1] += a0 * b1; acc[0][2] += a0 * b2; acc[0][3] += a0 * b3;
      acc[1][0] += a1 * b0; acc[1][1] += a1 * b1; acc[1][2] += a1 * b2; acc[1][3] += a1 * b3;
      acc[2][0] += a2 * b0; acc[2][1] += a2 * b1; acc[2][2] += a2 * b2; acc[2][3] += a2 * b3;
      acc[3][0] += a3 * b0; acc[3][1] += a3 * b1; acc[3][2] += a3 * b2; acc[3][3] += a3 * b3;
    }
    __syncthreads();
  }

  #pragma unroll
  for (int v = 0; v < 4; ++v) {
    int mrow = ca + ty + 16 * v;
    #pragma unroll
    for (int u = 0; u < 4; ++u) {
      int ncol = cb + tx + 16 * u;
      if (mrow < K_ && ncol < K_)
        atomicAdd(&rrg[(size_t)mrow * K_ + ncol], acc[v][u]);
    }
  }
}

// ---------------- symmetrize accumulated upper -> rr (full square, LD) -----
__global__ __launch_bounds__(256) void k_reduce(const double* __restrict__ rrg,
                                                double* __restrict__ rr)
{
  int idx = blockIdx.x * 256 + threadIdx.x;   // packed lower-tri index
  if (idx >= TRI_N) return;
  int i = (int)((sqrtf(8.f * (float)idx + 1.f) - 1.f) * 0.5f);
  while ((i + 1) * (i + 2) / 2 <= idx) ++i;
  while (i * (i + 1) / 2 > idx) --i;
  int j = idx - (i * (i + 1)) / 2;            // j <= i
  double s = rrg[(size_t)j * K_ + i];         // valid entries live at (min,max)
  rr[i * LD + j] = s;
  rr[j * LD + i] = s;
}

// ---------------- LDS-resident small linear algebra ------------------------
// 512 threads. Per panel: reg diag factor -> reg diag INVERSE (overwrites
// L_JJ with X_JJ) -> panel solve as chain-free GEMM vs X_JJ^T -> 4x4
// reg-tiled trailing update. Off-diag trtri + finals as before.
__global__ __launch_bounds__(512) void k_small2(
    const double* __restrict__ rr, const double* __restrict__ m,
    double* __restrict__ invsq, float* __restrict__ sq32,
    float* __restrict__ normv)
{
  extern __shared__ double smem[];
  double* tri = smem;               // 18336
  double* m_s = smem + TRI_N;       // 192
  double* w1  = m_s + 192;          // 192
  double* tmp = w1 + 192;           // 32*33 = 1056 (multi-use scratch)
  const int t = threadIdx.x;

  if (t < K_) m_s[t] = m[t];
  for (int i = t >> 5; i < K_; i += 16) {
    int base = (i * (i + 1)) / 2;
    for (int j = t & 31; j <= i; j += 32) {
      double v = rr[i * LD + j];
      tri[base + j] = (i == j) ? v + 1e-6 : v;
    }
  }
  __syncthreads();

  // ---- blocked Cholesky + in-loop diag inversion, 6 panels of 32 ----
  for (int J = 0; J < 6; ++J) {
    const int j0 = J * 32;
    const int nb = (K_ - j0 < 32) ? (K_ - j0) : 32;   // 32 x5, then 31

    // Phase A: wave 0 factors the diag block in registers (lane = row),
    // writes L_JJ + reciprocal diag; then lanes 0-31 invert it in registers
    // (column-per-lane forward-sub) and OVERWRITE the diag block with X_JJ.
    if (t < 64) {
      const int rl = t & 31;
      double a[32];
      #pragma unroll
      for (int c = 0; c < 32; ++c) {
        int i = j0 + rl;
        a[c] = (c <= rl && rl < nb) ? tri[(i * (i + 1)) / 2 + j0 + c] : 0.0;
      }
      #pragma unroll
      for (int k = 0; k < 32; ++k) {
        double akk = __shfl(a[k], k);
        double piv = sqrt(akk);
        double inv = 1.0 / piv;
        if (t == k) tmp[k] = inv;          // reciprocal diag
        a[k] = (rl == k) ? piv : a[k] * inv;
        #pragma unroll
        for (int c = k + 1; c < 32; ++c) {
          double lck = __shfl(a[k], c);    // L[j0+c][j0+k]
          if (c <= rl) a[c] -= a[k] * lck;
        }
      }
      if (t < 32 && rl < nb) {
        int i = j0 + rl;
        int rb = (i * (i + 1)) / 2 + j0;
        #pragma unroll
        for (int c = 0; c < 32; ++c)
          if (c <= rl) tri[rb + c] = a[c];
      }
      // in-wave visibility of the L writes; now invert: lane = column c
      if (t < 32) {
        const int c = t;
        double xcol[32];
        #pragma unroll
        for (int r = 0; r < 32; ++r) {
          int rr_ = (j0 + r < K_) ? j0 + r : K_ - 1;
          int rb2 = (rr_ * (rr_ + 1)) / 2 + j0;
          double s = (r == c) ? 1.0 : 0.0;
          #pragma unroll
          for (int k = 0; k < 32; ++k)
            if (k < r) s -= tri[rb2 + k] * xcol[k];
          xcol[r] = s * tmp[r];
        }
        #pragma unroll
        for (int r = 0; r < 32; ++r) {
          int rr_ = j0 + r;
          if (r >= c && rr_ < K_)
            tri[(rr_ * (rr_ + 1)) / 2 + j0 + c] = xcol[r];
        }
      }
    }
    __syncthreads();

    // Phase B: panel solve as GEMM: L_p = A_p * X_JJ^T (chain-free).
    // out[p][c] = sum_{k<=c} A[p][k] * X[j0+c][j0+k]; X reads broadcast.
    {
      int p = j0 + 32 + t;
      if (nb == 32 && p < K_) {
        int pb = (p * (p + 1)) / 2 + j0;
        double arow[32];
        #pragma unroll
        for (int k = 0; k < 32; ++k) arow[k] = tri[pb + k];
        #pragma unroll
        for (int c = 0; c < 32; ++c) {
          int cr = j0 + c;
          int cb2 = (cr * (cr + 1)) / 2 + j0;
          double s = 0.0;
          #pragma unroll
          for (int k = 0; k <= c; ++k)
            s += arow[k] * tri[cb2 + k];
          tri[pb + c] = s;     // row p exclusive to this thread
        }
      }
    }
    __syncthreads();

    // Phase C: trailing update A -= L_panel L_panel^T, 4x4 register tiles.
    {
      int s0 = j0 + 32;
      int n = K_ - s0;
      if (n > 0) {
        int R4 = (n + 3) >> 2;
        int T4 = R4 * (R4 + 1) / 2;
        for (int tile = t; tile < T4; tile += 512) {
          int ti = (int)((sqrtf(8.f * (float)tile + 1.f) - 1.f) * 0.5f);
          while ((ti + 1) * (ti + 2) / 2 <= tile) ++ti;
          while (ti * (ti + 1) / 2 > tile) --ti;
          int tj = tile - ti * (ti + 1) / 2;
          int r0 = s0 + ti * 4, c0 = s0 + tj * 4;
          int rb[4], cb[4];
          #pragma unroll
          for (int u = 0; u < 4; ++u) {
            int r = (r0 + u < K_) ? r0 + u : K_ - 1;
            rb[u] = (r * (r + 1)) / 2;
            int c = (c0 + u < K_) ? c0 + u : K_ - 1;
            cb[u] = (c * (c + 1)) / 2;
          }
          double acc[4][4];
          #pragma unroll
          for (int u = 0; u < 4; ++u)
            #pragma unroll
            for (int v2 = 0; v2 < 4; ++v2) acc[u][v2] = 0.0;
          #pragma unroll 4
          for (int p = 0; p < 32; ++p) {
            double lr[4], lc[4];
            #pragma unroll
            for (int u = 0; u < 4; ++u) {
              lr[u] = tri[rb[u] + j0 + p];
              lc[u] = tri[cb[u] + j0 + p];
            }
            #pragma unroll
            for (int u = 0; u < 4; ++u)
              #pragma unroll
              for (int v2 = 0; v2 < 4; ++v2) acc[u][v2] += lr[u] * lc[v2];
          }
          #pragma unroll
          for (int u = 0; u < 4; ++u) {
            int r = r0 + u;
            if (r < K_) {
              #pragma unroll
              for (int v2 = 0; v2 < 4; ++v2) {
                int c = c0 + v2;
                if (c <= r) tri[rb[u] + c] -= acc[u][v2];
              }
            }
          }
        }
      }
    }
    __syncthreads();
  }

  // ---- trtri off-diag blocks: X_IJ = -X_II (acc), acc = sum L/X products --
  for (int J = 0; J < 5; ++J) {
    const int j0 = J * 32;
    // stage X_JJ zero-padded (upper part = 0) into tmp, 33-stride
    for (int idx = t; idx < 32 * 32; idx += 512) {
      int kk = idx >> 5, c = idx & 31;
      int row = j0 + kk;
      double v = 0.0;
      if (kk >= c && row < K_)
        v = tri[(row * (row + 1)) / 2 + j0 + c];
      tmp[kk * 33 + c] = v;
    }
    __syncthreads();
    for (int I = J + 1; I < 6; ++I) {
      const int i0 = I * 32;
      const int r = t & 31;
      #pragma unroll
      for (int half = 0; half < 2; ++half) {
        const int c = (t >> 5) + 16 * half;     // 0..31
        int ri = i0 + r;
        int ric = (ri < K_) ? ri : K_ - 1;
        int rb = (ric * (ric + 1)) / 2;
        double acc = 0.0;
        #pragma unroll
        for (int kk = 0; kk < 32; ++kk)
          acc += tri[rb + j0 + kk] * tmp[kk * 33 + c];
        for (int kb = j0 + 32; kb < i0; kb += 32) {
          #pragma unroll
          for (int kk = 0; kk < 32; ++kk) {
            int k = kb + kk;
            acc += tri[rb + k] * tri[(k * (k + 1)) / 2 + j0 + c];
          }
        }
        double out = 0.0;
        #pragma unroll
        for (int k = 0; k < 32; ++k) {
          double av = __shfl(acc, (t & 32) | k, 64);
          double xv = (k <= r) ? tri[rb + i0 + k] : 0.0;
          out -= xv * av;
        }
        if (ri < K_)
          tri[rb + j0 + c] = out;
      }
      __syncthreads();
    }
  }

  if (t < K_) {
    int r = t, rb = (r * (r + 1)) / 2;
    double s = 0.0;
    #pragma unroll 8
    for (int p = 0; p <= r; ++p) s += tri[rb + p] * m_s[p];
    w1[r] = s;
  }
  __syncthreads();
  if (t < K_) {
    int i = t;
    double s2 = 0.0, s1 = 0.0;
    #pragma unroll 8
    for (int r = i; r < K_; ++r) {
      double xv = tri[(r * (r + 1)) / 2 + i];
      s2 += xv * xv;
      s1 += xv * w1[r];
    }
    double dii = s2;
    double q = 1.0 / dii;
    double sm_ = s1 / dii;
    double var = (q - sm_ * sm_ / (double)N_) / (double)(N_ - 1);
    double t1 = sqrt(var) + 1e-30;
    double om = t1 * t1;
    invsq[i] = 1.0 / sqrt(om);
    sq32[i] = sqrtf((float)om);
    tmp[i] = rr[i * LD + i] / om;
  }
  __syncthreads();
  if (t < 64) {
    double s = 0.0;
    for (int i = t; i < K_; i += 64) s += tmp[i];
    #pragma unroll
    for (int off = 32; off > 0; off >>= 1) s += __shfl_down(s, off);
    if (t == 0) *normv = (float)s;
  }
}

// ---------------- CholQR helper (operates on shQ K_ x MSUB, shS MSUB x 17) -
__device__ __forceinline__ void cholqr(double* shQ, double* shS, int t)
{
  // S = Q^T Q
  if (t < MSUB * MSUB) {
    int a = t & (MSUB - 1), b = t >> 4;
    double s = 0.0;
    for (int r = 0; r < K_; ++r) s += shQ[r * MSUB + a] * shQ[r * MSUB + b];
    shS[b * 17 + a] = s;
  }
  __syncthreads();
  // Cholesky 16x16 (lower)
  for (int k = 0; k < MSUB; ++k) {
    if (t == 0) shS[k * 17 + k] = sqrt(shS[k * 17 + k]);
    __syncthreads();
    if (t > k && t < MSUB) shS[t * 17 + k] /= shS[k * 17 + k];
    __syncthreads();
    if (t < MSUB * MSUB) {
      int r = t & (MSUB - 1), c = t >> 4;
      if (c > k && r >= c) shS[r * 17 + c] -= shS[r * 17 + k] * shS[c * 17 + k];
    }
    __syncthreads();
  }
  // rows solve: Qnew L^T = Qold
  if (t < K_) {
    double q[MSUB];
    #pragma unroll
    for (int c = 0; c < MSUB; ++c) {
      double v = shQ[t * MSUB + c];
      for (int p = 0; p < c; ++p) v -= q[p] * shS[c * 17 + p];
      q[c] = v / shS[c * 17 + c];
    }
    #pragma unroll
    for (int c = 0; c < MSUB; ++c) shQ[t * MSUB + c] = q[c];
  }
  __syncthreads();
}

// ---------------- one-block subspace iteration, top-16 eigenpairs ----------
__global__ __launch_bounds__(512) void k_sub(
    const double* __restrict__ rr, const double* __restrict__ invsq,
    float* __restrict__ W1, float* __restrict__ W2)
{
  extern __shared__ double dsm[];
  double* shQ  = dsm;                 // 3056
  double* shZ  = shQ + 3056;          // 3056
  double* shS  = shZ + 3056;          // 272 (16*17)
  double* Ws   = shS + 272;           // 272
  double* inv_s= Ws + 272;            // 192
  double* ev   = inv_s + 192;         // 16
  double* cs_  = ev + 16;             // 8
  double* sn_  = cs_ + 8;             // 8
  int* ipp  = (int*)(sn_ + 8);        // 8
  int* iqq  = ipp + 8;                // 8
  int* perm = iqq + 8;                // 16
  float* tri = (float*)(perm + 16);   // 18336
  const int t = threadIdx.x;

  if (t < K_) inv_s[t] = invsq[t];
  __syncthreads();
  // stage G lower triangle (f32): G_ij = rr_ij * invsq_i * invsq_j
  for (int i = t >> 4; i < K_; i += 32) {
    int base = (i * (i + 1)) / 2;
    double di = inv_s[i];
    for (int j = t & 15; j <= i; j += 16)
      tri[base + j] = (float)(rr[i * LD + j] * di * inv_s[j]);
  }
  __syncthreads();

  // init Q = G[:, 0:16]
  for (int idx = t; idx < K_ * MSUB; idx += 512) {
    int i = idx >> 4, c = idx & 15;
    float g = (i >= c) ? tri[(i * (i + 1)) / 2 + c] : tri[(c * (c + 1)) / 2 + i];
    shQ[idx] = (double)g;
  }
  __syncthreads();

  cholqr(shQ, shS, t);
  for (int it = 0; it < 4; ++it) {
    // copy Q -> Z
    for (int idx = t; idx < K_ * MSUB; idx += 512) shZ[idx] = shQ[idx];
    __syncthreads();
    // Q = G * Z (triangular-packed G), 2 rows x 4 cols per thread.
    // k ascends 0..K-1 for every output -> summation order identical.
    if (t < 96 * 4) {
      int i2 = t >> 2, c4 = t & 3;
      int r0 = 2 * i2, r1 = r0 + 1;
      int has1 = (r1 < K_);
      int rb0 = (r0 * (r0 + 1)) >> 1;
      int rb1 = has1 ? ((r1 * (r1 + 1)) >> 1) : rb0;
      int cb0 = c4 * 4;
      double s0a = 0.0, s0b = 0.0, s0c = 0.0, s0d = 0.0;
      double s1a = 0.0, s1b = 0.0, s1c = 0.0, s1d = 0.0;
      #pragma unroll 2
      for (int k = 0; k <= r0; ++k) {
        double g0 = (double)tri[rb0 + k];
        double g1 = (double)tri[rb1 + k];
        double za = shZ[k * MSUB + cb0],     zb = shZ[k * MSUB + cb0 + 1];
        double zc = shZ[k * MSUB + cb0 + 2], zd = shZ[k * MSUB + cb0 + 3];
        s0a += g0 * za; s0b += g0 * zb; s0c += g0 * zc; s0d += g0 * zd;
        s1a += g1 * za; s1b += g1 * zb; s1c += g1 * zc; s1d += g1 * zd;
      }
      if (has1) {
        double g0 = (double)tri[rb1 + r0];   // G[r0][r1] via symmetry
        double g1 = (double)tri[rb1 + r1];
        double za = shZ[r1 * MSUB + cb0],     zb = shZ[r1 * MSUB + cb0 + 1];
        double zc = shZ[r1 * MSUB + cb0 + 2], zd = shZ[r1 * MSUB + cb0 + 3];
        s0a += g0 * za; s0b += g0 * zb; s0c += g0 * zc; s0d += g0 * zd;
        s1a += g1 * za; s1b += g1 * zb; s1c += g1 * zc; s1d += g1 * zd;
      }
      int kk = ((r1 + 1) * (r1 + 2)) >> 1;
      #pragma unroll 2
      for (int k = r1 + 1; k < K_; ++k) {
        double g0 = (double)tri[kk + r0];
        double g1 = (double)tri[kk + r1];
        double za = shZ[k * MSUB + cb0],     zb = shZ[k * MSUB + cb0 + 1];
        double zc = shZ[k * MSUB + cb0 + 2], zd = shZ[k * MSUB + cb0 + 3];
        s0a += g0 * za; s0b += g0 * zb; s0c += g0 * zc; s0d += g0 * zd;
        s1a += g1 * za; s1b += g1 * zb; s1c += g1 * zc; s1d += g1 * zd;
        kk += k + 1;
      }
      shQ[r0 * MSUB + cb0]     = s0a;
      shQ[r0 * MSUB + cb0 + 1] = s0b;
      shQ[r0 * MSUB + cb0 + 2] = s0c;
      shQ[r0 * MSUB + cb0 + 3] = s0d;
      if (has1) {
        shQ[r1 * MSUB + cb0]     = s1a;
        shQ[r1 * MSUB + cb0 + 1] = s1b;
        shQ[r1 * MSUB + cb0 + 2] = s1c;
        shQ[r1 * MSUB + cb0 + 3] = s1d;
      }
    }
    __syncthreads();
    if (it < 3) cholqr(shQ, shS, t);
  }
  // here: shZ = Q_orth, shQ = G*Q_orth.  T = Z^T Q  -> shS
  if (t < MSUB * MSUB) {
    int a = t & 15, b = t >> 4;
    double s = 0.0;
    for (int r = 0; r < K_; ++r) s += shZ[r * MSUB + b] * shQ[r * MSUB + a];
    shS[b * 17 + a] = s;
  }
  // init Ws = I
  if (t < MSUB * 17) Ws[t] = 0.0;
  __syncthreads();
  if (t < MSUB) Ws[t * 17 + t] = 1.0;
  __syncthreads();
  // Jacobi eigensolve of 16x16 T
  for (int sweep = 0; sweep < 6; ++sweep) {
    for (int round = 0; round < 15; ++round) {
      if (t < 8) {
        int ia = (t == 0) ? 0 : (1 + ((t - 1 + round) % 15));
        int ib = 1 + ((14 - t + round) % 15);
        int p = ia < ib ? ia : ib;
        int q = ia < ib ? ib : ia;
        double app = shS[p * 17 + p], aqq = shS[q * 17 + q], apq = shS[p * 17 + q];
        double c = 1.0, s = 0.0;
        if (fabs(apq) > 1e-30 * (fabs(app) + fabs(aqq)) && apq != 0.0) {
          double tau = (aqq - app) / (2.0 * apq);
          double tt = (tau >= 0.0 ? 1.0 : -1.0) / (fabs(tau) + sqrt(1.0 + tau * tau));
          c = 1.0 / sqrt(1.0 + tt * tt); s = tt * c;
        }
        cs_[t] = c; sn_[t] = s; ipp[t] = p; iqq[t] = q;
      }
      __syncthreads();
      if (t < 128) {   // column rotations of T and Ws
        int i = t & 15, mI = t >> 4;
        int p = ipp[mI], q = iqq[mI];
        double c = cs_[mI], s = sn_[mI];
        double u = shS[i * 17 + p], v = shS[i * 17 + q];
        shS[i * 17 + p] = c * u - s * v; shS[i * 17 + q] = s * u + c * v;
        double wu = Ws[i * 17 + p], wv = Ws[i * 17 + q];
        Ws[i * 17 + p] = c * wu - s * wv; Ws[i * 17 + q] = s * wu + c * wv;
      }
      __syncthreads();
      if (t < 128) {   // row rotations of T
        int j = t & 15, mI = t >> 4;
        int p = ipp[mI], q = iqq[mI];
        double c = cs_[mI], s = sn_[mI];
        double u = shS[p * 17 + j], v = shS[q * 17 + j];
        shS[p * 17 + j] = c * u - s * v; shS[q * 17 + j] = s * u + c * v;
      }
      __syncthreads();
    }
  }
  if (t == 0) {
    for (int i = 0; i < MSUB; ++i) { ev[i] = shS[i * 17 + i]; perm[i] = i; }
    for (int i = 0; i < MSUB; ++i) {
      int best = i;
      for (int j = i + 1; j < MSUB; ++j)
        if (ev[perm[j]] > ev[perm[best]]) best = j;
      int tp = perm[i]; perm[i] = perm[best]; perm[best] = tp;
    }
  }
  __syncthreads();
  // E = Q_orth * Ws (sorted); W1[i][c] = invsq_i * E ; W2[c][i] = E * sqrt(om_i)
  for (int idx = t; idx < K_ * MSUB; idx += 512) {
    int i = idx >> 4, c = idx & 15;
    int pc_ = perm[c];
    double e = 0.0;
    #pragma unroll
    for (int p = 0; p < MSUB; ++p) e += shZ[i * MSUB + p] * Ws[p * 17 + pc_];
    W1[i * MSUB + c] = (float)(inv_s[i] * e);
    W2[c * K_ + i]   = (float)(e / inv_s[i]);
  }
}

// ---------------- pc = x * W1 (f32), channel-major output ------------------
__global__ __launch_bounds__(256) void k_pc(const float* __restrict__ x,
                                            const float* __restrict__ W1,
                                            float* __restrict__ pc)
{
  __shared__ float xs[32][192];
  __shared__ float w1s[K_ * MSUB];
  int t = threadIdx.x;
  long n0 = (long)blockIdx.x * 32;
  for (int idx = t; idx < K_ * MSUB; idx += 256) w1s[idx] = W1[idx];
  for (int idx = t; idx < 32 * K_; idx += 256) {
    int row = idx / K_, col = idx - row * K_;
    xs[row][col] = x[(n0 + row) * K_ + col];
  }
  __syncthreads();
  int c = t & 15, nl = t >> 4;         // nl in [0,16)
  float a0 = 0.f, a1 = 0.f;
  for (int k = 0; k < K_; ++k) {
    float w = w1s[k * MSUB + c];
    a0 += xs[nl][k] * w;
    a1 += xs[nl + 16][k] * w;
  }
  __syncthreads();
  float* ts = &xs[0][0];               // reuse as 16x33 transpose buffer
  ts[c * 33 + nl]      = a0;
  ts[c * 33 + nl + 16] = a1;
  __syncthreads();
  for (int idx = t; idx < MSUB * 32; idx += 256) {
    int cc = idx >> 5, nn = idx & 31;
    pc[(size_t)cc * N_ + n0 + nn] = ts[cc * 33 + nn];
  }
}

// ---------------- DWT: vertical analysis pass ------------------------------
__global__ __launch_bounds__(256) void k_dwtv(const float* __restrict__ in,
                                              float* __restrict__ outv, int s)
{
  long gid = (long)blockIdx.x * 256 + threadIdx.x;
  int h = s >> 1;
  long per = (long)h * s;
  if (gid >= MSUB * per) return;
  int ch = (int)(gid / per);
  long rem = gid - (long)ch * per;
  int r = (int)(rem / s);
  int col = (int)(rem - (long)r * s);
  const float* cin = in + (long)ch * s * s;
  float la = 0.f, ld_ = 0.f;
  int base = 2 * r;
  #pragma unroll
  for (int l = 0; l < 10; ++l) {
    int rr_ = base + l; if (rr_ >= s) rr_ -= s;
    float v = cin[(long)rr_ * s + col];
    la += c_lo[l] * v; ld_ += c_hi[l] * v;
  }
  float* cout = outv + (long)ch * s * s;
  cout[(long)r * s + col] = la;
  cout[(long)(h + r) * s + col] = ld_;
}

// ---------------- DWT: horizontal analysis pass ----------------------------
__global__ __launch_bounds__(256) void k_dwth(const float* __restrict__ inv,
                                              float* __restrict__ llout,
                                              float* __restrict__ coef,
                                              int s, long offL, int last)
{
  long gid = (long)blockIdx.x * 256 + threadIdx.x;
  int h = s >> 1;
  long per = (long)s * h;
  if (gid >= MSUB * per) return;
  int ch = (int)(gid / per);
  long rem = gid - (long)ch * per;
  int r = (int)(rem / h);
  int mcol = (int)(rem - (long)r * h);
  const float* row = inv + (long)ch * s * s + (long)r * s;
  float lo = 0.f, hi = 0.f;
  int base = 2 * mcol;
  #pragma unroll
  for (int l = 0; l < 10; ++l) {
    int cc = base + l; if (cc >= s) cc -= s;
    float v = row[cc];
    lo += c_lo[l] * v; hi += c_hi[l] * v;
  }
  float* cslab = coef + (size_t)ch * N_ + offL;
  if (r < h) {
    llout[(size_t)ch * h * h + (long)r * h + mcol] = lo;
    if (last) coef[(size_t)ch * N_ + 147312 + (long)r * h + mcol] = lo;
    cslab[(long)r * h + mcol] = hi;
  } else {
    int rd = r - h;
    cslab[(long)h * h + (long)rd * h + mcol] = lo;
    cslab[(long)2 * h * h + (long)rd * h + mcol] = hi;
  }
}

// ---------------- SURE statistics per channel ------------------------------
__global__ __launch_bounds__(256) void k_stats(const float* __restrict__ coef,
                                               float* __restrict__ stats)
{
  int ch = blockIdx.x;
  int t = threadIdx.x;
  float T2[NT];
  {
    double stop = sqrt(log(147456.0));
    double step = stop / 14.0;
    for (int i = 0; i < NT; ++i) {
      double td = (i == 14) ? stop : (double)i * step;
      float tf = (float)td;
      T2[i] = tf * tf;
    }
  }
  float cn = 0.f, sm[NT], ct[NT];
  #pragma unroll
  for (int i = 0; i < NT; ++i) { sm[i] = 0.f; ct[i] = 0.f; }
  const float* base = coef + (size_t)ch * N_;
  for (int idx = t; idx < N_; idx += 256) {
    float v = base[idx];
    float v2 = v * v;
    cn += v2;
    #pragma unroll
    for (int i = 0; i < NT; ++i) {
      sm[i] += fminf(v2, T2[i]);
      ct[i] += (v2 > T2[i]) ? 1.0f : 0.0f;
    }
  }
  // in-wave shfl reduction (1 barrier total, replaces 248 barriers)
  __shared__ float red2[4][32];
  int lane = t & 63, wv = t >> 6;
  for (int a = 0; a < 31; ++a) {
    float val = (a == 0) ? cn : ((a < 16) ? sm[a - 1] : ct[a - 16]);
    #pragma unroll
    for (int off = 32; off > 0; off >>= 1) val += __shfl_down(val, off);
    if (lane == 0) red2[wv][a] = val;
  }
  __syncthreads();
  if (t < 31)
    stats[ch * 31 + t] = red2[0][t] + red2[1][t] + red2[2][t] + red2[3][t];
}

// ---------------- SURE scan + rank -----------------------------------------
__global__ void k_rank(const float* __restrict__ stats,
                       const float* __restrict__ normv, int* __restrict__ rankp)
{
  if (threadIdx.x != 0 || blockIdx.x != 0) return;
  float c_const = *normv - 28164096.0f;
  float acc[NT];
  for (int i = 0; i < NT; ++i) acc[i] = 0.f;
  float minsure[MSUB];
  for (int r = 0; r < MSUB; ++r) {
    float cn = stats[r * 31 + 0];
    float mn = 3.4e38f;
    for (int i = 0; i < NT; ++i) {
      float sure = stats[r * 31 + 1 + i] + 2.0f * stats[r * 31 + 16 + i] - cn;
      float s_r = acc[i] + sure + c_const;
      acc[i] = acc[i] + s_r;
      if (s_r < mn) mn = s_r;
    }
    minsure[r] = mn;
  }
  int rank = -1;
  for (int r = 2; r < MSUB; ++r) {
    if (minsure[r] > minsure[r - 1]) { rank = r; break; }
  }
  if (rank < 0) rank = MSUB - 1;
  *rankp = rank;
}

// ---------------- output: out = sqrt(omega) .* (pc[:, :rank] @ vh) ---------
__global__ __launch_bounds__(256) void k_out(const float* __restrict__ pc,
                                             const float* __restrict__ W2,
                                             const int* __restrict__ rankp,
                                             float* __restrict__ out)
{
  long gid = (long)blockIdx.x * 256 + threadIdx.x;
  int n = (int)(gid / K_);
  int j = (int)(gid - (long)n * K_);
  int rank = *rankp;
  float acc = 0.f;
  for (int c = 0; c < rank; ++c)
    acc += pc[(size_t)c * N_ + n] * W2[c * K_ + j];
  out[gid] = acc;
}

extern "C" void kernel_launch(void* const* d_in, const int* in_sizes, int n_in,
                              void* d_out, int out_size, void* d_ws, size_t ws_size,
                              hipStream_t stream)
{
  if (n_in < 1 || in_sizes[0] != N_ * K_) return;
  const float* x = (const float*)d_in[0];
  float* out = (float*)d_out;
  (void)out_size;

  char* w = (char*)d_ws;
  size_t off = 0;
  auto alloc = [&](size_t bytes) -> char* {
    char* p = w + off;
    off = (off + bytes + 255) & ~(size_t)255;
    return p;
  };
  double* m_    = (double*)alloc(K_ * 8);
  double* rrp   = (double*)alloc((size_t)K_ * K_ * 8);   // atomically-accumulated Gram
  double* rr    = (double*)alloc((size_t)K_ * LD * 8);
  double* invsq = (double*)alloc(K_ * 8);
  float*  sq32  = (float*)alloc(K_ * 4);
  float*  normv = (float*)alloc(256);
  float*  W1    = (float*)alloc((size_t)K_ * MSUB * 4);
  float*  W2    = (float*)alloc((size_t)MSUB * K_ * 4);
  float*  pc    = (float*)alloc((size_t)MSUB * N_ * 4);
  float*  tmpv  = (float*)alloc((size_t)MSUB * N_ * 4);
  float*  coef  = (float*)alloc((size_t)MSUB * N_ * 4);
  float*  curA  = (float*)alloc((size_t)MSUB * 192 * 192 * 4);
  float*  curB  = (float*)alloc((size_t)MSUB * 96 * 96 * 4);
  float*  stats = (float*)alloc((size_t)MSUB * 31 * 4);
  int*    rankp = (int*)alloc(256);
  if (off > ws_size) return;

  hipMemsetAsync(m_, 0, K_ * sizeof(double), stream);
  hipMemsetAsync(rrp, 0, (size_t)K_ * K_ * sizeof(double), stream);

  hipFuncSetAttribute(reinterpret_cast<const void*>(k_small2),
                      hipFuncAttributeMaxDynamicSharedMemorySize, SMEM_SZ);
  hipFuncSetAttribute(reinterpret_cast<const void*>(k_sub),
                      hipFuncAttributeMaxDynamicSharedMemorySize, SMEM2_SZ);

  k_colsum<<<N_ / 512, 256, 0, stream>>>(x, m_);
  k_rr<<<NPAIR * NSPLIT, 256, 0, stream>>>(x, rrp);
  k_reduce<<<(TRI_N + 255) / 256, 256, 0, stream>>>(rrp, rr);
  k_small2<<<1, 512, SMEM_SZ, stream>>>(rr, m_, invsq, sq32, normv);
  k_sub<<<1, 512, SMEM2_SZ, stream>>>(rr, invsq, W1, W2);
  k_pc<<<N_ / 32, 256, 0, stream>>>(x, W1, pc);

  int   sizes[5] = {384, 192, 96, 48, 24};
  long  offs[5]  = {0, 110592, 138240, 145152, 146880};
  float* lls[5]  = {curA, curB, curA, curB, curA};
  const float* curin = pc;
  for (int lev = 0; lev < 5; ++lev) {
    int s = sizes[lev], h = s >> 1;
    long nth = (long)MSUB * h * s;
    k_dwtv<<<(int)((nth + 255) / 256), 256, 0, stream>>>(curin, tmpv, s);
    k_dwth<<<(int)((nth + 255) / 256), 256, 0, stream>>>(tmpv, lls[lev], coef,
                                                         s, offs[lev],
                                                         lev == 4 ? 1 : 0);
    curin = lls[lev];
  }

  k_stats<<<MSUB, 256, 0, stream>>>(coef, stats);
  k_rank<<<1, 64, 0, stream>>>(stats, normv, rankp);
  k_out<<<(N_ * K_) / 256, 256, 0, stream>>>(pc, W2, rankp, out);
}

// Round 6
// 1646.410 us; speedup vs baseline: 1.0483x; 1.0483x over previous
//
#include <hip/hip_runtime.h>
#include <math.h>

#define K_     191
#define LD     192
#define N_     147456
#define MSUB   16
#define NT     15
#define TRI_N  18336   // 191*192/2
#define SMEM_SZ ((TRI_N + 192 + 192 + 1056) * 8)
// k_sub dynamic LDS: 6880 doubles + 32 ints + 18336 floats
#define SMEM2_SZ (6880 * 8 + 32 * 4 + TRI_N * 4)

// k_rr geometry: 64-wide col blocks, 6 pairs, 128 K-splits
#define NPAIR  6
#define NSPLIT 128
#define CHUNK  (N_ / NSPLIT)   // 1152
#define RSTEP  32

// db5 decomposition filters (pywt convention), f32 as in reference
__constant__ float c_lo[10] = {
  0.003335725285001549f, -0.012580751999015526f, -0.006241490213011705f,
  0.07757149384006515f,  -0.03224486958502952f, -0.24229488706619015f,
  0.13842814590110342f,   0.7243085284385744f,   0.6038292697974729f,
  0.160102397974125f };
__constant__ float c_hi[10] = {
  0.160102397974125f,    -0.6038292697974729f,   0.7243085284385744f,
 -0.13842814590110342f,  -0.24229488706619015f,  0.03224486958502952f,
  0.07757149384006515f,   0.006241490213011705f,-0.012580751999015526f,
 -0.003335725285001549f };

// ---------------- column sums of x (f64), for the regression mean ----------
__global__ __launch_bounds__(256) void k_colsum(const float* __restrict__ x,
                                                double* __restrict__ m)
{
  int t = threadIdx.x;
  long base = (long)blockIdx.x * 512;
  if (t < K_) {
    double s = 0.0;
    const float* p = x + base * K_ + t;
    for (int r = 0; r < 512; ++r) s += (double)p[(long)r * K_];
    atomicAdd(&m[t], s);
  }
}

// ---------------- rr = x^T x, register-tiled VALU f64, split-K atomics -----
__global__ __launch_bounds__(256, 3) void k_rr(const float* __restrict__ x,
                                               double* __restrict__ rrg)
{
  __shared__ double Asd[RSTEP][64];
  __shared__ double Bsd[RSTEP][64];

  const int bid   = blockIdx.x;
  const int split = bid & (NSPLIT - 1);
  const int pair  = bid >> 7;
  const int BI[6] = {0, 0, 0, 1, 1, 2};
  const int BJ[6] = {0, 1, 2, 1, 2, 2};
  const int bi = BI[pair], bj = BJ[pair];
  const int ca = bi * 64, cb = bj * 64;

  const int t  = threadIdx.x;
  const int tx = t & 15, ty = t >> 4;
  const long n0 = (long)split * CHUNK;

  double acc[4][4];
  #pragma unroll
  for (int v = 0; v < 4; ++v)
    #pragma unroll
    for (int u = 0; u < 4; ++u) acc[v][u] = 0.0;

  for (int r0 = 0; r0 < CHUNK; r0 += RSTEP) {
    for (int s = t; s < RSTEP * 16; s += 256) {
      int row = s >> 4, g = s & 15;
      long gr = (n0 + r0 + row) * (long)K_;
      int c4a = ca + g * 4, c4b = cb + g * 4;
      #pragma unroll
      for (int e = 0; e < 4; ++e) {
        Asd[row][g * 4 + e] = (c4a + e < K_) ? (double)x[gr + c4a + e] : 0.0;
        Bsd[row][g * 4 + e] = (c4b + e < K_) ? (double)x[gr + c4b + e] : 0.0;
      }
    }
    __syncthreads();
    #pragma unroll 4
    for (int k = 0; k < RSTEP; ++k) {
      double a0 = Asd[k][ty],      a1 = Asd[k][ty + 16];
      double a2 = Asd[k][ty + 32], a3 = Asd[k][ty + 48];
      double b0 = Bsd[k][tx],      b1 = Bsd[k][tx + 16];
      double b2 = Bsd[k][tx + 32], b3 = Bsd[k][tx + 48];
      acc[0][0] += a0 * b0; acc[0][1] += a0 * b1; acc[0][2] += a0 * b2; acc[0][3] += a0 * b3;
      acc[1][0] += a1 * b0; acc[1][1] += a1 * b1; acc[1][2] += a1 * b2; acc[1][3] += a1 * b3;
      acc[2][0] += a2 * b0; acc[2][1] += a2 * b1; acc[2][2] += a2 * b2; acc[2][3] += a2 * b3;
      acc[3][0] += a3 * b0; acc[3][1] += a3 * b1; acc[3][2] += a3 * b2; acc[3][3] += a3 * b3;
    }
    __syncthreads();
  }

  #pragma unroll
  for (int v = 0; v < 4; ++v) {
    int mrow = ca + ty + 16 * v;
    #pragma unroll
    for (int u = 0; u < 4; ++u) {
      int ncol = cb + tx + 16 * u;
      if (mrow < K_ && ncol < K_)
        atomicAdd(&rrg[(size_t)mrow * K_ + ncol], acc[v][u]);
    }
  }
}

// ---------------- symmetrize accumulated upper -> rr (full square, LD) -----
__global__ __launch_bounds__(256) void k_reduce(const double* __restrict__ rrg,
                                                double* __restrict__ rr)
{
  int idx = blockIdx.x * 256 + threadIdx.x;   // packed lower-tri index
  if (idx >= TRI_N) return;
  int i = (int)((sqrtf(8.f * (float)idx + 1.f) - 1.f) * 0.5f);
  while ((i + 1) * (i + 2) / 2 <= idx) ++i;
  while (i * (i + 1) / 2 > idx) --i;
  int j = idx - (i * (i + 1)) / 2;            // j <= i
  double s = rrg[(size_t)j * K_ + i];         // valid entries live at (min,max)
  rr[i * LD + j] = s;
  rr[j * LD + i] = s;
}

// ---------------- LDS-resident small linear algebra ------------------------
// 512 threads (round-4 verified structure: no spills, VGPR=92).
// Blocked Cholesky (reg diag factor + serial panel solve + 4x4 reg-tiled
// update), trtri diag in registers, off-diag via staging + in-wave shfl.
__global__ __launch_bounds__(512) void k_small2(
    const double* __restrict__ rr, const double* __restrict__ m,
    double* __restrict__ invsq, float* __restrict__ sq32,
    float* __restrict__ normv)
{
  extern __shared__ double smem[];
  double* tri = smem;               // 18336
  double* m_s = smem + TRI_N;       // 192
  double* w1  = m_s + 192;          // 192
  double* tmp = w1 + 192;           // 32*33 = 1056 (multi-use scratch)
  const int t = threadIdx.x;

  if (t < K_) m_s[t] = m[t];
  for (int i = t >> 5; i < K_; i += 16) {
    int base = (i * (i + 1)) / 2;
    for (int j = t & 31; j <= i; j += 32) {
      double v = rr[i * LD + j];
      tri[base + j] = (i == j) ? v + 1e-6 : v;
    }
  }
  __syncthreads();

  // ---- blocked Cholesky, 6 panels of 32 columns ----
  for (int J = 0; J < 6; ++J) {
    const int j0 = J * 32;
    const int nb = (K_ - j0 < 32) ? (K_ - j0) : 32;   // 32 x5, then 31

    // Phase A: wave 0 factors the diag block in registers (lane = row).
    if (t < 64) {
      const int rl = t & 31;
      double a[32];
      #pragma unroll
      for (int c = 0; c < 32; ++c) {
        int i = j0 + rl;
        a[c] = (c <= rl && rl < nb) ? tri[(i * (i + 1)) / 2 + j0 + c] : 0.0;
      }
      #pragma unroll
      for (int k = 0; k < 32; ++k) {
        double akk = __shfl(a[k], k);
        double piv = sqrt(akk);
        double inv = 1.0 / piv;
        if (t == k) tmp[k] = inv;          // reciprocal diag for panel solve
        a[k] = (rl == k) ? piv : a[k] * inv;
        #pragma unroll
        for (int c = k + 1; c < 32; ++c) {
          double lck = __shfl(a[k], c);    // L[j0+c][j0+k]
          if (c <= rl) a[c] -= a[k] * lck;
        }
      }
      if (t < 32 && rl < nb) {
        int i = j0 + rl;
        int rb = (i * (i + 1)) / 2 + j0;
        #pragma unroll
        for (int c = 0; c < 32; ++c)
          if (c <= rl) tri[rb + c] = a[c];
      }
    }
    __syncthreads();

    // Phase B: panel solve, one row per thread.
    {
      int p = j0 + 32 + t;
      if (nb == 32 && p < K_) {
        int pb = (p * (p + 1)) / 2 + j0;
        double v[32];
        #pragma unroll
        for (int c = 0; c < 32; ++c) v[c] = tri[pb + c];
        #pragma unroll
        for (int c = 0; c < 32; ++c) {
          double s = v[c];
          #pragma unroll
          for (int q = 0; q < c; ++q) {
            int cc = j0 + c;
            s -= v[q] * tri[(cc * (cc + 1)) / 2 + j0 + q];
          }
          v[c] = s * tmp[c];
        }
        #pragma unroll
        for (int c = 0; c < 32; ++c) tri[pb + c] = v[c];
      }
    }
    __syncthreads();

    // Phase C: trailing update A -= L_panel L_panel^T, 4x4 register tiles.
    {
      int s0 = j0 + 32;
      int n = K_ - s0;
      if (n > 0) {
        int R4 = (n + 3) >> 2;
        int T4 = R4 * (R4 + 1) / 2;
        for (int tile = t; tile < T4; tile += 512) {
          int ti = (int)((sqrtf(8.f * (float)tile + 1.f) - 1.f) * 0.5f);
          while ((ti + 1) * (ti + 2) / 2 <= tile) ++ti;
          while (ti * (ti + 1) / 2 > tile) --ti;
          int tj = tile - ti * (ti + 1) / 2;
          int r0 = s0 + ti * 4, c0 = s0 + tj * 4;
          int rb[4], cb[4];
          #pragma unroll
          for (int u = 0; u < 4; ++u) {
            int r = (r0 + u < K_) ? r0 + u : K_ - 1;
            rb[u] = (r * (r + 1)) / 2;
            int c = (c0 + u < K_) ? c0 + u : K_ - 1;
            cb[u] = (c * (c + 1)) / 2;
          }
          double acc[4][4];
          #pragma unroll
          for (int u = 0; u < 4; ++u)
            #pragma unroll
            for (int v2 = 0; v2 < 4; ++v2) acc[u][v2] = 0.0;
          #pragma unroll 4
          for (int p = 0; p < 32; ++p) {
            double lr[4], lc[4];
            #pragma unroll
            for (int u = 0; u < 4; ++u) {
              lr[u] = tri[rb[u] + j0 + p];
              lc[u] = tri[cb[u] + j0 + p];
            }
            #pragma unroll
            for (int u = 0; u < 4; ++u)
              #pragma unroll
              for (int v2 = 0; v2 < 4; ++v2) acc[u][v2] += lr[u] * lc[v2];
          }
          #pragma unroll
          for (int u = 0; u < 4; ++u) {
            int r = r0 + u;
            if (r < K_) {
              #pragma unroll
              for (int v2 = 0; v2 < 4; ++v2) {
                int c = c0 + v2;
                if (c <= r) tri[rb[u] + c] -= acc[u][v2];
              }
            }
          }
        }
      }
    }
    __syncthreads();
  }

  // ---- trtri diag blocks: X_JJ = L_JJ^{-1}, column-per-thread registers ---
  for (int J = 0; J < 6; ++J) {
    const int j0 = J * 32;
    const int nb = (K_ - j0 < 32) ? (K_ - j0) : 32;
    if (t < 32) {
      int rd = (t < nb) ? j0 + t : K_ - 1;
      tmp[t] = 1.0 / tri[(rd * (rd + 1)) / 2 + rd];
    }
    __syncthreads();
    double xcol[32];
    if (t < 32) {
      const int c = t;
      #pragma unroll
      for (int r = 0; r < 32; ++r) {
        int rr_ = (j0 + r < K_) ? j0 + r : K_ - 1;
        int rb = (rr_ * (rr_ + 1)) / 2 + j0;
        double s = (r == c) ? 1.0 : 0.0;
        #pragma unroll
        for (int k = 0; k < 32; ++k)
          if (k < r) s -= tri[rb + k] * xcol[k];
        xcol[r] = s * tmp[r];
      }
    }
    __syncthreads();
    if (t < nb) {
      #pragma unroll
      for (int r = 0; r < 32; ++r) {
        int rr_ = j0 + r;
        if (r >= t && rr_ < K_)
          tri[(rr_ * (rr_ + 1)) / 2 + j0 + t] = xcol[r];
      }
    }
    __syncthreads();
  }

  // ---- trtri off-diag blocks: X_IJ = -X_II (acc), acc = sum L/X products --
  for (int J = 0; J < 5; ++J) {
    const int j0 = J * 32;
    // stage X_JJ zero-padded (upper part = 0) into tmp, 33-stride
    for (int idx = t; idx < 32 * 32; idx += 512) {
      int kk = idx >> 5, c = idx & 31;
      int row = j0 + kk;
      double v = 0.0;
      if (kk >= c && row < K_)
        v = tri[(row * (row + 1)) / 2 + j0 + c];
      tmp[kk * 33 + c] = v;
    }
    __syncthreads();
    for (int I = J + 1; I < 6; ++I) {
      const int i0 = I * 32;
      const int r = t & 31;
      #pragma unroll
      for (int half = 0; half < 2; ++half) {
        const int c = (t >> 5) + 16 * half;     // 0..31
        int ri = i0 + r;
        int ric = (ri < K_) ? ri : K_ - 1;
        int rb = (ric * (ric + 1)) / 2;
        double acc = 0.0;
        #pragma unroll
        for (int kk = 0; kk < 32; ++kk)
          acc += tri[rb + j0 + kk] * tmp[kk * 33 + c];
        for (int kb = j0 + 32; kb < i0; kb += 32) {
          #pragma unroll
          for (int kk = 0; kk < 32; ++kk) {
            int k = kb + kk;
            acc += tri[rb + k] * tri[(k * (k + 1)) / 2 + j0 + c];
          }
        }
        double out = 0.0;
        #pragma unroll
        for (int k = 0; k < 32; ++k) {
          double av = __shfl(acc, (t & 32) | k, 64);
          double xv = (k <= r) ? tri[rb + i0 + k] : 0.0;
          out -= xv * av;
        }
        if (ri < K_)
          tri[rb + j0 + c] = out;
      }
      __syncthreads();
    }
  }

  if (t < K_) {
    int r = t, rb = (r * (r + 1)) / 2;
    double s = 0.0;
    #pragma unroll 8
    for (int p = 0; p <= r; ++p) s += tri[rb + p] * m_s[p];
    w1[r] = s;
  }
  __syncthreads();
  if (t < K_) {
    int i = t;
    double s2 = 0.0, s1 = 0.0;
    #pragma unroll 8
    for (int r = i; r < K_; ++r) {
      double xv = tri[(r * (r + 1)) / 2 + i];
      s2 += xv * xv;
      s1 += xv * w1[r];
    }
    double dii = s2;
    double q = 1.0 / dii;
    double sm_ = s1 / dii;
    double var = (q - sm_ * sm_ / (double)N_) / (double)(N_ - 1);
    double t1 = sqrt(var) + 1e-30;
    double om = t1 * t1;
    invsq[i] = 1.0 / sqrt(om);
    sq32[i] = sqrtf((float)om);
    tmp[i] = rr[i * LD + i] / om;
  }
  __syncthreads();
  if (t < 64) {
    double s = 0.0;
    for (int i = t; i < K_; i += 64) s += tmp[i];
    #pragma unroll
    for (int off = 32; off > 0; off >>= 1) s += __shfl_down(s, off);
    if (t == 0) *normv = (float)s;
  }
}

// ---------------- CholQR helper (operates on shQ K_ x MSUB, shS MSUB x 17) -
__device__ __forceinline__ void cholqr(double* shQ, double* shS, int t)
{
  // S = Q^T Q
  if (t < MSUB * MSUB) {
    int a = t & (MSUB - 1), b = t >> 4;
    double s = 0.0;
    for (int r = 0; r < K_; ++r) s += shQ[r * MSUB + a] * shQ[r * MSUB + b];
    shS[b * 17 + a] = s;
  }
  __syncthreads();
  // Cholesky 16x16 (lower)
  for (int k = 0; k < MSUB; ++k) {
    if (t == 0) shS[k * 17 + k] = sqrt(shS[k * 17 + k]);
    __syncthreads();
    if (t > k && t < MSUB) shS[t * 17 + k] /= shS[k * 17 + k];
    __syncthreads();
    if (t < MSUB * MSUB) {
      int r = t & (MSUB - 1), c = t >> 4;
      if (c > k && r >= c) shS[r * 17 + c] -= shS[r * 17 + k] * shS[c * 17 + k];
    }
    __syncthreads();
  }
  // rows solve: Qnew L^T = Qold
  if (t < K_) {
    double q[MSUB];
    #pragma unroll
    for (int c = 0; c < MSUB; ++c) {
      double v = shQ[t * MSUB + c];
      for (int p = 0; p < c; ++p) v -= q[p] * shS[c * 17 + p];
      q[c] = v / shS[c * 17 + c];
    }
    #pragma unroll
    for (int c = 0; c < MSUB; ++c) shQ[t * MSUB + c] = q[c];
  }
  __syncthreads();
}

// ---------------- one-block subspace iteration, top-16 eigenpairs ----------
__global__ __launch_bounds__(512) void k_sub(
    const double* __restrict__ rr, const double* __restrict__ invsq,
    float* __restrict__ W1, float* __restrict__ W2)
{
  extern __shared__ double dsm[];
  double* shQ  = dsm;                 // 3056
  double* shZ  = shQ + 3056;          // 3056
  double* shS  = shZ + 3056;          // 272 (16*17)
  double* Ws   = shS + 272;           // 272
  double* inv_s= Ws + 272;            // 192
  double* ev   = inv_s + 192;         // 16
  double* cs_  = ev + 16;             // 8
  double* sn_  = cs_ + 8;             // 8
  int* ipp  = (int*)(sn_ + 8);        // 8
  int* iqq  = ipp + 8;                // 8
  int* perm = iqq + 8;                // 16
  float* tri = (float*)(perm + 16);   // 18336
  const int t = threadIdx.x;

  if (t < K_) inv_s[t] = invsq[t];
  __syncthreads();
  // stage G lower triangle (f32): G_ij = rr_ij * invsq_i * invsq_j
  for (int i = t >> 4; i < K_; i += 32) {
    int base = (i * (i + 1)) / 2;
    double di = inv_s[i];
    for (int j = t & 15; j <= i; j += 16)
      tri[base + j] = (float)(rr[i * LD + j] * di * inv_s[j]);
  }
  __syncthreads();

  // init Q = G[:, 0:16]
  for (int idx = t; idx < K_ * MSUB; idx += 512) {
    int i = idx >> 4, c = idx & 15;
    float g = (i >= c) ? tri[(i * (i + 1)) / 2 + c] : tri[(c * (c + 1)) / 2 + i];
    shQ[idx] = (double)g;
  }
  __syncthreads();

  cholqr(shQ, shS, t);
  for (int it = 0; it < 4; ++it) {
    // copy Q -> Z
    for (int idx = t; idx < K_ * MSUB; idx += 512) shZ[idx] = shQ[idx];
    __syncthreads();
    // Q = G * Z (triangular-packed G), 2 rows x 4 cols per thread.
    // k ascends 0..K-1 for every output -> summation order identical.
    if (t < 96 * 4) {
      int i2 = t >> 2, c4 = t & 3;
      int r0 = 2 * i2, r1 = r0 + 1;
      int has1 = (r1 < K_);
      int rb0 = (r0 * (r0 + 1)) >> 1;
      int rb1 = has1 ? ((r1 * (r1 + 1)) >> 1) : rb0;
      int cb0 = c4 * 4;
      double s0a = 0.0, s0b = 0.0, s0c = 0.0, s0d = 0.0;
      double s1a = 0.0, s1b = 0.0, s1c = 0.0, s1d = 0.0;
      #pragma unroll 2
      for (int k = 0; k <= r0; ++k) {
        double g0 = (double)tri[rb0 + k];
        double g1 = (double)tri[rb1 + k];
        double za = shZ[k * MSUB + cb0],     zb = shZ[k * MSUB + cb0 + 1];
        double zc = shZ[k * MSUB + cb0 + 2], zd = shZ[k * MSUB + cb0 + 3];
        s0a += g0 * za; s0b += g0 * zb; s0c += g0 * zc; s0d += g0 * zd;
        s1a += g1 * za; s1b += g1 * zb; s1c += g1 * zc; s1d += g1 * zd;
      }
      if (has1) {
        double g0 = (double)tri[rb1 + r0];   // G[r0][r1] via symmetry
        double g1 = (double)tri[rb1 + r1];
        double za = shZ[r1 * MSUB + cb0],     zb = shZ[r1 * MSUB + cb0 + 1];
        double zc = shZ[r1 * MSUB + cb0 + 2], zd = shZ[r1 * MSUB + cb0 + 3];
        s0a += g0 * za; s0b += g0 * zb; s0c += g0 * zc; s0d += g0 * zd;
        s1a += g1 * za; s1b += g1 * zb; s1c += g1 * zc; s1d += g1 * zd;
      }
      int kk = ((r1 + 1) * (r1 + 2)) >> 1;
      #pragma unroll 2
      for (int k = r1 + 1; k < K_; ++k) {
        double g0 = (double)tri[kk + r0];
        double g1 = (double)tri[kk + r1];
        double za = shZ[k * MSUB + cb0],     zb = shZ[k * MSUB + cb0 + 1];
        double zc = shZ[k * MSUB + cb0 + 2], zd = shZ[k * MSUB + cb0 + 3];
        s0a += g0 * za; s0b += g0 * zb; s0c += g0 * zc; s0d += g0 * zd;
        s1a += g1 * za; s1b += g1 * zb; s1c += g1 * zc; s1d += g1 * zd;
        kk += k + 1;
      }
      shQ[r0 * MSUB + cb0]     = s0a;
      shQ[r0 * MSUB + cb0 + 1] = s0b;
      shQ[r0 * MSUB + cb0 + 2] = s0c;
      shQ[r0 * MSUB + cb0 + 3] = s0d;
      if (has1) {
        shQ[r1 * MSUB + cb0]     = s1a;
        shQ[r1 * MSUB + cb0 + 1] = s1b;
        shQ[r1 * MSUB + cb0 + 2] = s1c;
        shQ[r1 * MSUB + cb0 + 3] = s1d;
      }
    }
    __syncthreads();
    if (it < 3) cholqr(shQ, shS, t);
  }
  // here: shZ = Q_orth, shQ = G*Q_orth.  T = Z^T Q  -> shS
  if (t < MSUB * MSUB) {
    int a = t & 15, b = t >> 4;
    double s = 0.0;
    for (int r = 0; r < K_; ++r) s += shZ[r * MSUB + b] * shQ[r * MSUB + a];
    shS[b * 17 + a] = s;
  }
  // init Ws = I
  if (t < MSUB * 17) Ws[t] = 0.0;
  __syncthreads();
  if (t < MSUB) Ws[t * 17 + t] = 1.0;
  __syncthreads();
  // Jacobi eigensolve of 16x16 T
  for (int sweep = 0; sweep < 6; ++sweep) {
    for (int round = 0; round < 15; ++round) {
      if (t < 8) {
        int ia = (t == 0) ? 0 : (1 + ((t - 1 + round) % 15));
        int ib = 1 + ((14 - t + round) % 15);
        int p = ia < ib ? ia : ib;
        int q = ia < ib ? ib : ia;
        double app = shS[p * 17 + p], aqq = shS[q * 17 + q], apq = shS[p * 17 + q];
        double c = 1.0, s = 0.0;
        if (fabs(apq) > 1e-30 * (fabs(app) + fabs(aqq)) && apq != 0.0) {
          double tau = (aqq - app) / (2.0 * apq);
          double tt = (tau >= 0.0 ? 1.0 : -1.0) / (fabs(tau) + sqrt(1.0 + tau * tau));
          c = 1.0 / sqrt(1.0 + tt * tt); s = tt * c;
        }
        cs_[t] = c; sn_[t] = s; ipp[t] = p; iqq[t] = q;
      }
      __syncthreads();
      if (t < 128) {   // column rotations of T and Ws
        int i = t & 15, mI = t >> 4;
        int p = ipp[mI], q = iqq[mI];
        double c = cs_[mI], s = sn_[mI];
        double u = shS[i * 17 + p], v = shS[i * 17 + q];
        shS[i * 17 + p] = c * u - s * v; shS[i * 17 + q] = s * u + c * v;
        double wu = Ws[i * 17 + p], wv = Ws[i * 17 + q];
        Ws[i * 17 + p] = c * wu - s * wv; Ws[i * 17 + q] = s * wu + c * wv;
      }
      __syncthreads();
      if (t < 128) {   // row rotations of T
        int j = t & 15, mI = t >> 4;
        int p = ipp[mI], q = iqq[mI];
        double c = cs_[mI], s = sn_[mI];
        double u = shS[p * 17 + j], v = shS[q * 17 + j];
        shS[p * 17 + j] = c * u - s * v; shS[q * 17 + j] = s * u + c * v;
      }
      __syncthreads();
    }
  }
  if (t == 0) {
    for (int i = 0; i < MSUB; ++i) { ev[i] = shS[i * 17 + i]; perm[i] = i; }
    for (int i = 0; i < MSUB; ++i) {
      int best = i;
      for (int j = i + 1; j < MSUB; ++j)
        if (ev[perm[j]] > ev[perm[best]]) best = j;
      int tp = perm[i]; perm[i] = perm[best]; perm[best] = tp;
    }
  }
  __syncthreads();
  // E = Q_orth * Ws (sorted); W1[i][c] = invsq_i * E ; W2[c][i] = E * sqrt(om_i)
  for (int idx = t; idx < K_ * MSUB; idx += 512) {
    int i = idx >> 4, c = idx & 15;
    int pc_ = perm[c];
    double e = 0.0;
    #pragma unroll
    for (int p = 0; p < MSUB; ++p) e += shZ[i * MSUB + p] * Ws[p * 17 + pc_];
    W1[i * MSUB + c] = (float)(inv_s[i] * e);
    W2[c * K_ + i]   = (float)(e / inv_s[i]);
  }
}

// ---------------- pc = x * W1 (f32), channel-major output ------------------
__global__ __launch_bounds__(256) void k_pc(const float* __restrict__ x,
                                            const float* __restrict__ W1,
                                            float* __restrict__ pc)
{
  __shared__ float xs[32][192];
  __shared__ float w1s[K_ * MSUB];
  int t = threadIdx.x;
  long n0 = (long)blockIdx.x * 32;
  for (int idx = t; idx < K_ * MSUB; idx += 256) w1s[idx] = W1[idx];
  for (int idx = t; idx < 32 * K_; idx += 256) {
    int row = idx / K_, col = idx - row * K_;
    xs[row][col] = x[(n0 + row) * K_ + col];
  }
  __syncthreads();
  int c = t & 15, nl = t >> 4;         // nl in [0,16)
  float a0 = 0.f, a1 = 0.f;
  for (int k = 0; k < K_; ++k) {
    float w = w1s[k * MSUB + c];
    a0 += xs[nl][k] * w;
    a1 += xs[nl + 16][k] * w;
  }
  __syncthreads();
  float* ts = &xs[0][0];               // reuse as 16x33 transpose buffer
  ts[c * 33 + nl]      = a0;
  ts[c * 33 + nl + 16] = a1;
  __syncthreads();
  for (int idx = t; idx < MSUB * 32; idx += 256) {
    int cc = idx >> 5, nn = idx & 31;
    pc[(size_t)cc * N_ + n0 + nn] = ts[cc * 33 + nn];
  }
}

// ---------------- DWT: vertical analysis pass ------------------------------
__global__ __launch_bounds__(256) void k_dwtv(const float* __restrict__ in,
                                              float* __restrict__ outv, int s)
{
  long gid = (long)blockIdx.x * 256 + threadIdx.x;
  int h = s >> 1;
  long per = (long)h * s;
  if (gid >= MSUB * per) return;
  int ch = (int)(gid / per);
  long rem = gid - (long)ch * per;
  int r = (int)(rem / s);
  int col = (int)(rem - (long)r * s);
  const float* cin = in + (long)ch * s * s;
  float la = 0.f, ld_ = 0.f;
  int base = 2 * r;
  #pragma unroll
  for (int l = 0; l < 10; ++l) {
    int rr_ = base + l; if (rr_ >= s) rr_ -= s;
    float v = cin[(long)rr_ * s + col];
    la += c_lo[l] * v; ld_ += c_hi[l] * v;
  }
  float* cout = outv + (long)ch * s * s;
  cout[(long)r * s + col] = la;
  cout[(long)(h + r) * s + col] = ld_;
}

// ---------------- DWT: horizontal analysis pass ----------------------------
__global__ __launch_bounds__(256) void k_dwth(const float* __restrict__ inv,
                                              float* __restrict__ llout,
                                              float* __restrict__ coef,
                                              int s, long offL, int last)
{
  long gid = (long)blockIdx.x * 256 + threadIdx.x;
  int h = s >> 1;
  long per = (long)s * h;
  if (gid >= MSUB * per) return;
  int ch = (int)(gid / per);
  long rem = gid - (long)ch * per;
  int r = (int)(rem / h);
  int mcol = (int)(rem - (long)r * h);
  const float* row = inv + (long)ch * s * s + (long)r * s;
  float lo = 0.f, hi = 0.f;
  int base = 2 * mcol;
  #pragma unroll
  for (int l = 0; l < 10; ++l) {
    int cc = base + l; if (cc >= s) cc -= s;
    float v = row[cc];
    lo += c_lo[l] * v; hi += c_hi[l] * v;
  }
  float* cslab = coef + (size_t)ch * N_ + offL;
  if (r < h) {
    llout[(size_t)ch * h * h + (long)r * h + mcol] = lo;
    if (last) coef[(size_t)ch * N_ + 147312 + (long)r * h + mcol] = lo;
    cslab[(long)r * h + mcol] = hi;
  } else {
    int rd = r - h;
    cslab[(long)h * h + (long)rd * h + mcol] = lo;
    cslab[(long)2 * h * h + (long)rd * h + mcol] = hi;
  }
}

// ---------------- SURE statistics per channel ------------------------------
__global__ __launch_bounds__(256) void k_stats(const float* __restrict__ coef,
                                               float* __restrict__ stats)
{
  int ch = blockIdx.x;
  int t = threadIdx.x;
  float T2[NT];
  {
    double stop = sqrt(log(147456.0));
    double step = stop / 14.0;
    for (int i = 0; i < NT; ++i) {
      double td = (i == 14) ? stop : (double)i * step;
      float tf = (float)td;
      T2[i] = tf * tf;
    }
  }
  float cn = 0.f, sm[NT], ct[NT];
  #pragma unroll
  for (int i = 0; i < NT; ++i) { sm[i] = 0.f; ct[i] = 0.f; }
  const float* base = coef + (size_t)ch * N_;
  for (int idx = t; idx < N_; idx += 256) {
    float v = base[idx];
    float v2 = v * v;
    cn += v2;
    #pragma unroll
    for (int i = 0; i < NT; ++i) {
      sm[i] += fminf(v2, T2[i]);
      ct[i] += (v2 > T2[i]) ? 1.0f : 0.0f;
    }
  }
  // in-wave shfl reduction (1 barrier total, replaces 248 barriers)
  __shared__ float red2[4][32];
  int lane = t & 63, wv = t >> 6;
  for (int a = 0; a < 31; ++a) {
    float val = (a == 0) ? cn : ((a < 16) ? sm[a - 1] : ct[a - 16]);
    #pragma unroll
    for (int off = 32; off > 0; off >>= 1) val += __shfl_down(val, off);
    if (lane == 0) red2[wv][a] = val;
  }
  __syncthreads();
  if (t < 31)
    stats[ch * 31 + t] = red2[0][t] + red2[1][t] + red2[2][t] + red2[3][t];
}

// ---------------- SURE scan + rank -----------------------------------------
__global__ void k_rank(const float* __restrict__ stats,
                       const float* __restrict__ normv, int* __restrict__ rankp)
{
  if (threadIdx.x != 0 || blockIdx.x != 0) return;
  float c_const = *normv - 28164096.0f;
  float acc[NT];
  for (int i = 0; i < NT; ++i) acc[i] = 0.f;
  float minsure[MSUB];
  for (int r = 0; r < MSUB; ++r) {
    float cn = stats[r * 31 + 0];
    float mn = 3.4e38f;
    for (int i = 0; i < NT; ++i) {
      float sure = stats[r * 31 + 1 + i] + 2.0f * stats[r * 31 + 16 + i] - cn;
      float s_r = acc[i] + sure + c_const;
      acc[i] = acc[i] + s_r;
      if (s_r < mn) mn = s_r;
    }
    minsure[r] = mn;
  }
  int rank = -1;
  for (int r = 2; r < MSUB; ++r) {
    if (minsure[r] > minsure[r - 1]) { rank = r; break; }
  }
  if (rank < 0) rank = MSUB - 1;
  *rankp = rank;
}

// ---------------- output: out = sqrt(omega) .* (pc[:, :rank] @ vh) ---------
__global__ __launch_bounds__(256) void k_out(const float* __restrict__ pc,
                                             const float* __restrict__ W2,
                                             const int* __restrict__ rankp,
                                             float* __restrict__ out)
{
  long gid = (long)blockIdx.x * 256 + threadIdx.x;
  int n = (int)(gid / K_);
  int j = (int)(gid - (long)n * K_);
  int rank = *rankp;
  float acc = 0.f;
  for (int c = 0; c < rank; ++c)
    acc += pc[(size_t)c * N_ + n] * W2[c * K_ + j];
  out[gid] = acc;
}

extern "C" void kernel_launch(void* const* d_in, const int* in_sizes, int n_in,
                              void* d_out, int out_size, void* d_ws, size_t ws_size,
                              hipStream_t stream)
{
  if (n_in < 1 || in_sizes[0] != N_ * K_) return;
  const float* x = (const float*)d_in[0];
  float* out = (float*)d_out;
  (void)out_size;

  char* w = (char*)d_ws;
  size_t off = 0;
  auto alloc = [&](size_t bytes) -> char* {
    char* p = w + off;
    off = (off + bytes + 255) & ~(size_t)255;
    return p;
  };
  double* m_    = (double*)alloc(K_ * 8);
  double* rrp   = (double*)alloc((size_t)K_ * K_ * 8);   // atomically-accumulated Gram
  double* rr    = (double*)alloc((size_t)K_ * LD * 8);
  double* invsq = (double*)alloc(K_ * 8);
  float*  sq32  = (float*)alloc(K_ * 4);
  float*  normv = (float*)alloc(256);
  float*  W1    = (float*)alloc((size_t)K_ * MSUB * 4);
  float*  W2    = (float*)alloc((size_t)MSUB * K_ * 4);
  float*  pc    = (float*)alloc((size_t)MSUB * N_ * 4);
  float*  tmpv  = (float*)alloc((size_t)MSUB * N_ * 4);
  float*  coef  = (float*)alloc((size_t)MSUB * N_ * 4);
  float*  curA  = (float*)alloc((size_t)MSUB * 192 * 192 * 4);
  float*  curB  = (float*)alloc((size_t)MSUB * 96 * 96 * 4);
  float*  stats = (float*)alloc((size_t)MSUB * 31 * 4);
  int*    rankp = (int*)alloc(256);
  if (off > ws_size) return;

  hipMemsetAsync(m_, 0, K_ * sizeof(double), stream);
  hipMemsetAsync(rrp, 0, (size_t)K_ * K_ * sizeof(double), stream);

  hipFuncSetAttribute(reinterpret_cast<const void*>(k_small2),
                      hipFuncAttributeMaxDynamicSharedMemorySize, SMEM_SZ);
  hipFuncSetAttribute(reinterpret_cast<const void*>(k_sub),
                      hipFuncAttributeMaxDynamicSharedMemorySize, SMEM2_SZ);

  k_colsum<<<N_ / 512, 256, 0, stream>>>(x, m_);
  k_rr<<<NPAIR * NSPLIT, 256, 0, stream>>>(x, rrp);
  k_reduce<<<(TRI_N + 255) / 256, 256, 0, stream>>>(rrp, rr);
  k_small2<<<1, 512, SMEM_SZ, stream>>>(rr, m_, invsq, sq32, normv);
  k_sub<<<1, 512, SMEM2_SZ, stream>>>(rr, invsq, W1, W2);
  k_pc<<<N_ / 32, 256, 0, stream>>>(x, W1, pc);

  int   sizes[5] = {384, 192, 96, 48, 24};
  long  offs[5]  = {0, 110592, 138240, 145152, 146880};
  float* lls[5]  = {curA, curB, curA, curB, curA};
  const float* curin = pc;
  for (int lev = 0; lev < 5; ++lev) {
    int s = sizes[lev], h = s >> 1;
    long nth = (long)MSUB * h * s;
    k_dwtv<<<(int)((nth + 255) / 256), 256, 0, stream>>>(curin, tmpv, s);
    k_dwth<<<(int)((nth + 255) / 256), 256, 0, stream>>>(tmpv, lls[lev], coef,
                                                         s, offs[lev],
                                                         lev == 4 ? 1 : 0);
    curin = lls[lev];
  }

  k_stats<<<MSUB, 256, 0, stream>>>(coef, stats);
  k_rank<<<1, 64, 0, stream>>>(stats, normv, rankp);
  k_out<<<(N_ * K_) / 256, 256, 0, stream>>>(pc, W2, rankp, out);
}

// Round 7
// 1476.389 us; speedup vs baseline: 1.1690x; 1.1152x over previous
//
#include <hip/hip_runtime.h>
#include <math.h>

#define K_     191
#define LD     192
#define N_     147456
#define MSUB   16
#define NT     15
#define TRI_N  18336   // 191*192/2
#define SMEM_CHOL  ((TRI_N + 1056) * 8)
#define SMEM_SOLVE ((TRI_N + 192 + 192 + 192) * 8)
// k_sub dynamic LDS: 6880 doubles + 32 ints + 18336 floats
#define SMEM2_SZ (6880 * 8 + 32 * 4 + TRI_N * 4)

// k_rr geometry: 64-wide col blocks, 6 pairs, 128 K-splits
#define NPAIR  6
#define NSPLIT 128
#define CHUNK  (N_ / NSPLIT)   // 1152
#define RSTEP  32

// db5 decomposition filters (pywt convention), f32 as in reference
__constant__ float c_lo[10] = {
  0.003335725285001549f, -0.012580751999015526f, -0.006241490213011705f,
  0.07757149384006515f,  -0.03224486958502952f, -0.24229488706619015f,
  0.13842814590110342f,   0.7243085284385744f,   0.6038292697974729f,
  0.160102397974125f };
__constant__ float c_hi[10] = {
  0.160102397974125f,    -0.6038292697974729f,   0.7243085284385744f,
 -0.13842814590110342f,  -0.24229488706619015f,  0.03224486958502952f,
  0.07757149384006515f,   0.006241490213011705f,-0.012580751999015526f,
 -0.003335725285001549f };

// ---------------- column sums of x (f64), for the regression mean ----------
__global__ __launch_bounds__(256) void k_colsum(const float* __restrict__ x,
                                                double* __restrict__ m)
{
  int t = threadIdx.x;
  long base = (long)blockIdx.x * 512;
  if (t < K_) {
    double s = 0.0;
    const float* p = x + base * K_ + t;
    for (int r = 0; r < 512; ++r) s += (double)p[(long)r * K_];
    atomicAdd(&m[t], s);
  }
}

// ---------------- rr = x^T x, register-tiled VALU f64, split-K atomics -----
__global__ __launch_bounds__(256, 3) void k_rr(const float* __restrict__ x,
                                               double* __restrict__ rrg)
{
  __shared__ double Asd[RSTEP][64];
  __shared__ double Bsd[RSTEP][64];

  const int bid   = blockIdx.x;
  const int split = bid & (NSPLIT - 1);
  const int pair  = bid >> 7;
  const int BI[6] = {0, 0, 0, 1, 1, 2};
  const int BJ[6] = {0, 1, 2, 1, 2, 2};
  const int bi = BI[pair], bj = BJ[pair];
  const int ca = bi * 64, cb = bj * 64;

  const int t  = threadIdx.x;
  const int tx = t & 15, ty = t >> 4;
  const long n0 = (long)split * CHUNK;

  double acc[4][4];
  #pragma unroll
  for (int v = 0; v < 4; ++v)
    #pragma unroll
    for (int u = 0; u < 4; ++u) acc[v][u] = 0.0;

  for (int r0 = 0; r0 < CHUNK; r0 += RSTEP) {
    for (int s = t; s < RSTEP * 16; s += 256) {
      int row = s >> 4, g = s & 15;
      long gr = (n0 + r0 + row) * (long)K_;
      int c4a = ca + g * 4, c4b = cb + g * 4;
      #pragma unroll
      for (int e = 0; e < 4; ++e) {
        Asd[row][g * 4 + e] = (c4a + e < K_) ? (double)x[gr + c4a + e] : 0.0;
        Bsd[row][g * 4 + e] = (c4b + e < K_) ? (double)x[gr + c4b + e] : 0.0;
      }
    }
    __syncthreads();
    #pragma unroll 4
    for (int k = 0; k < RSTEP; ++k) {
      double a0 = Asd[k][ty],      a1 = Asd[k][ty + 16];
      double a2 = Asd[k][ty + 32], a3 = Asd[k][ty + 48];
      double b0 = Bsd[k][tx],      b1 = Bsd[k][tx + 16];
      double b2 = Bsd[k][tx + 32], b3 = Bsd[k][tx + 48];
      acc[0][0] += a0 * b0; acc[0][1] += a0 * b1; acc[0][2] += a0 * b2; acc[0][3] += a0 * b3;
      acc[1][0] += a1 * b0; acc[1][1] += a1 * b1; acc[1][2] += a1 * b2; acc[1][3] += a1 * b3;
      acc[2][0] += a2 * b0; acc[2][1] += a2 * b1; acc[2][2] += a2 * b2; acc[2][3] += a2 * b3;
      acc[3][0] += a3 * b0; acc[3][1] += a3 * b1; acc[3][2] += a3 * b2; acc[3][3] += a3 * b3;
    }
    __syncthreads();
  }

  #pragma unroll
  for (int v = 0; v < 4; ++v) {
    int mrow = ca + ty + 16 * v;
    #pragma unroll
    for (int u = 0; u < 4; ++u) {
      int ncol = cb + tx + 16 * u;
      if (mrow < K_ && ncol < K_)
        atomicAdd(&rrg[(size_t)mrow * K_ + ncol], acc[v][u]);
    }
  }
}

// ---------------- symmetrize accumulated upper -> rr (full square, LD) -----
__global__ __launch_bounds__(256) void k_reduce(const double* __restrict__ rrg,
                                                double* __restrict__ rr)
{
  int idx = blockIdx.x * 256 + threadIdx.x;   // packed lower-tri index
  if (idx >= TRI_N) return;
  int i = (int)((sqrtf(8.f * (float)idx + 1.f) - 1.f) * 0.5f);
  while ((i + 1) * (i + 2) / 2 <= idx) ++i;
  while (i * (i + 1) / 2 > idx) --i;
  int j = idx - (i * (i + 1)) / 2;            // j <= i
  double s = rrg[(size_t)j * K_ + i];         // valid entries live at (min,max)
  rr[i * LD + j] = s;
  rr[j * LD + i] = s;
}

// ---------------- blocked Cholesky only (exports packed L + recip diag) ----
// 512 threads, round-4 verified structure (no spills).
__global__ __launch_bounds__(512) void k_chol(
    const double* __restrict__ rr, double* __restrict__ Lg,
    double* __restrict__ rdg)
{
  extern __shared__ double smem[];
  double* tri = smem;               // 18336
  double* tmp = smem + TRI_N;       // 1056 scratch (recip diag per panel)
  const int t = threadIdx.x;

  for (int i = t >> 5; i < K_; i += 16) {
    int base = (i * (i + 1)) / 2;
    for (int j = t & 31; j <= i; j += 32) {
      double v = rr[i * LD + j];
      tri[base + j] = (i == j) ? v + 1e-6 : v;
    }
  }
  __syncthreads();

  for (int J = 0; J < 6; ++J) {
    const int j0 = J * 32;
    const int nb = (K_ - j0 < 32) ? (K_ - j0) : 32;   // 32 x5, then 31

    // Phase A: wave 0 factors the diag block in registers (lane = row).
    if (t < 64) {
      const int rl = t & 31;
      double a[32];
      #pragma unroll
      for (int c = 0; c < 32; ++c) {
        int i = j0 + rl;
        a[c] = (c <= rl && rl < nb) ? tri[(i * (i + 1)) / 2 + j0 + c] : 0.0;
      }
      #pragma unroll
      for (int k = 0; k < 32; ++k) {
        double akk = __shfl(a[k], k);
        double piv = sqrt(akk);
        double inv = 1.0 / piv;
        if (t == k) {
          tmp[k] = inv;                          // recip diag for panel solve
          if (j0 + k < K_) rdg[j0 + k] = inv;    // export
        }
        a[k] = (rl == k) ? piv : a[k] * inv;
        #pragma unroll
        for (int c = k + 1; c < 32; ++c) {
          double lck = __shfl(a[k], c);    // L[j0+c][j0+k]
          if (c <= rl) a[c] -= a[k] * lck;
        }
      }
      if (t < 32 && rl < nb) {
        int i = j0 + rl;
        int rb = (i * (i + 1)) / 2 + j0;
        #pragma unroll
        for (int c = 0; c < 32; ++c)
          if (c <= rl) tri[rb + c] = a[c];
      }
    }
    __syncthreads();

    // Phase B: panel solve, one row per thread.
    {
      int p = j0 + 32 + t;
      if (nb == 32 && p < K_) {
        int pb = (p * (p + 1)) / 2 + j0;
        double v[32];
        #pragma unroll
        for (int c = 0; c < 32; ++c) v[c] = tri[pb + c];
        #pragma unroll
        for (int c = 0; c < 32; ++c) {
          double s = v[c];
          #pragma unroll
          for (int q = 0; q < c; ++q) {
            int cc = j0 + c;
            s -= v[q] * tri[(cc * (cc + 1)) / 2 + j0 + q];
          }
          v[c] = s * tmp[c];
        }
        #pragma unroll
        for (int c = 0; c < 32; ++c) tri[pb + c] = v[c];
      }
    }
    __syncthreads();

    // Phase C: trailing update A -= L_panel L_panel^T, 4x4 register tiles.
    {
      int s0 = j0 + 32;
      int n = K_ - s0;
      if (n > 0) {
        int R4 = (n + 3) >> 2;
        int T4 = R4 * (R4 + 1) / 2;
        for (int tile = t; tile < T4; tile += 512) {
          int ti = (int)((sqrtf(8.f * (float)tile + 1.f) - 1.f) * 0.5f);
          while ((ti + 1) * (ti + 2) / 2 <= tile) ++ti;
          while (ti * (ti + 1) / 2 > tile) --ti;
          int tj = tile - ti * (ti + 1) / 2;
          int r0 = s0 + ti * 4, c0 = s0 + tj * 4;
          int rb[4], cb[4];
          #pragma unroll
          for (int u = 0; u < 4; ++u) {
            int r = (r0 + u < K_) ? r0 + u : K_ - 1;
            rb[u] = (r * (r + 1)) / 2;
            int c = (c0 + u < K_) ? c0 + u : K_ - 1;
            cb[u] = (c * (c + 1)) / 2;
          }
          double acc[4][4];
          #pragma unroll
          for (int u = 0; u < 4; ++u)
            #pragma unroll
            for (int v2 = 0; v2 < 4; ++v2) acc[u][v2] = 0.0;
          #pragma unroll 4
          for (int p = 0; p < 32; ++p) {
            double lr[4], lc[4];
            #pragma unroll
            for (int u = 0; u < 4; ++u) {
              lr[u] = tri[rb[u] + j0 + p];
              lc[u] = tri[cb[u] + j0 + p];
            }
            #pragma unroll
            for (int u = 0; u < 4; ++u)
              #pragma unroll
              for (int v2 = 0; v2 < 4; ++v2) acc[u][v2] += lr[u] * lc[v2];
          }
          #pragma unroll
          for (int u = 0; u < 4; ++u) {
            int r = r0 + u;
            if (r < K_) {
              #pragma unroll
              for (int v2 = 0; v2 < 4; ++v2) {
                int c = c0 + v2;
                if (c <= r) tri[rb[u] + c] -= acc[u][v2];
              }
            }
          }
        }
      }
    }
    __syncthreads();
  }

  // export packed L
  for (int idx = t; idx < TRI_N; idx += 512) Lg[idx] = tri[idx];
}

// ---------------- per-column solves of L x = e_i, parallel across blocks ---
// Block i (< K_): forward solve, emit s2[i] = ||column i of L^{-1}||^2.
// Block K_: y = L^{-1} m, then z = L^{-T} y  ->  z = R^{-1} m.
// x kept in owner-lane registers (k%64==lane, slot k/64); wave-synchronous.
__global__ __launch_bounds__(256) void k_csolve(
    const double* __restrict__ Lg, const double* __restrict__ rdg,
    const double* __restrict__ mg, double* __restrict__ s2g,
    double* __restrict__ zg)
{
  extern __shared__ double ssm[];
  double* Ls   = ssm;               // 18336 (staged from row `start`)
  double* rd_s = Ls + TRI_N;        // 192
  double* m_sh = rd_s + 192;        // 192
  double* ys   = m_sh + 192;        // 192
  const int t = threadIdx.x;
  const int bid = blockIdx.x;

  const int start = (bid < K_) ? (bid * (bid + 1)) / 2 : 0;
  for (int idx = start + t; idx < TRI_N; idx += 256) Ls[idx] = Lg[idx];
  if (t < K_) { rd_s[t] = rdg[t]; m_sh[t] = mg[t]; }
  __syncthreads();

  if (t >= 64) return;              // wave 0 solves; no barriers after
  const int l = t;

  if (bid < K_) {
    const int i = bid;
    double x0 = 0.0, x1 = 0.0, x2 = 0.0;
    {
      double rdi = rd_s[i];
      if ((i & 63) == l) {
        int sl = i >> 6;
        if (sl == 0) x0 = rdi; else if (sl == 1) x1 = rdi; else x2 = rdi;
      }
    }
    for (int r = i + 1; r < K_; ++r) {
      int rb = (r * (r + 1)) >> 1;
      double partial = 0.0;
      { int k = l;       if (k < r) partial += Ls[rb + k] * x0; }
      { int k = l + 64;  if (k < r) partial += Ls[rb + k] * x1; }
      { int k = l + 128; if (k < r) partial += Ls[rb + k] * x2; }
      #pragma unroll
      for (int mm = 32; mm > 0; mm >>= 1) partial += __shfl_xor(partial, mm);
      double val = -partial * rd_s[r];
      if ((r & 63) == l) {
        int sl = r >> 6;
        if (sl == 0) x0 = val; else if (sl == 1) x1 = val; else x2 = val;
      }
    }
    double s2p = x0 * x0 + x1 * x1 + x2 * x2;
    #pragma unroll
    for (int mm = 32; mm > 0; mm >>= 1) s2p += __shfl_xor(s2p, mm);
    if (l == 0) s2g[i] = s2p;
  } else {
    // forward: L y = m
    double y0 = 0.0, y1 = 0.0, y2 = 0.0;
    for (int r = 0; r < K_; ++r) {
      int rb = (r * (r + 1)) >> 1;
      double partial = 0.0;
      { int k = l;       if (k < r) partial += Ls[rb + k] * y0; }
      { int k = l + 64;  if (k < r) partial += Ls[rb + k] * y1; }
      { int k = l + 128; if (k < r) partial += Ls[rb + k] * y2; }
      #pragma unroll
      for (int mm = 32; mm > 0; mm >>= 1) partial += __shfl_xor(partial, mm);
      double val = (m_sh[r] - partial) * rd_s[r];
      if ((r & 63) == l) {
        int sl = r >> 6;
        if (sl == 0) y0 = val; else if (sl == 1) y1 = val; else y2 = val;
      }
      if (l == 0) ys[r] = val;
    }
    // backward: L^T z = y
    double z0 = 0.0, z1 = 0.0, z2 = 0.0;
    for (int r = K_ - 1; r >= 0; --r) {
      double partial = 0.0;
      { int k = l;       if (k > r && k < K_) partial += Ls[((k * (k + 1)) >> 1) + r] * z0; }
      { int k = l + 64;  if (k > r && k < K_) partial += Ls[((k * (k + 1)) >> 1) + r] * z1; }
      { int k = l + 128; if (k > r && k < K_) partial += Ls[((k * (k + 1)) >> 1) + r] * z2; }
      #pragma unroll
      for (int mm = 32; mm > 0; mm >>= 1) partial += __shfl_xor(partial, mm);
      double val = (ys[r] - partial) * rd_s[r];
      if ((r & 63) == l) {
        int sl = r >> 6;
        if (sl == 0) z0 = val; else if (sl == 1) z1 = val; else z2 = val;
      }
      if (l == 0) zg[r] = val;
    }
  }
}

// ---------------- finals: omega, invsq, normv ------------------------------
__global__ __launch_bounds__(256) void k_finals(
    const double* __restrict__ rr, const double* __restrict__ s2g,
    const double* __restrict__ zg, double* __restrict__ invsq,
    float* __restrict__ normv)
{
  __shared__ double tmps[K_];
  const int t = threadIdx.x;
  if (t < K_) {
    double dii = s2g[t];
    double q = 1.0 / dii;
    double sm_ = zg[t] / dii;
    double var = (q - sm_ * sm_ / (double)N_) / (double)(N_ - 1);
    double t1 = sqrt(var) + 1e-30;
    double om = t1 * t1;
    invsq[t] = 1.0 / sqrt(om);
    tmps[t] = rr[t * LD + t] / om;
  }
  __syncthreads();
  if (t < 64) {
    double s = 0.0;
    for (int i = t; i < K_; i += 64) s += tmps[i];
    #pragma unroll
    for (int off = 32; off > 0; off >>= 1) s += __shfl_down(s, off);
    if (t == 0) *normv = (float)s;
  }
}

// ---------------- CholQR helper (operates on shQ K_ x MSUB, shS MSUB x 17) -
__device__ __forceinline__ void cholqr(double* shQ, double* shS, int t)
{
  // S = Q^T Q
  if (t < MSUB * MSUB) {
    int a = t & (MSUB - 1), b = t >> 4;
    double s = 0.0;
    for (int r = 0; r < K_; ++r) s += shQ[r * MSUB + a] * shQ[r * MSUB + b];
    shS[b * 17 + a] = s;
  }
  __syncthreads();
  // Cholesky 16x16 (lower)
  for (int k = 0; k < MSUB; ++k) {
    if (t == 0) shS[k * 17 + k] = sqrt(shS[k * 17 + k]);
    __syncthreads();
    if (t > k && t < MSUB) shS[t * 17 + k] /= shS[k * 17 + k];
    __syncthreads();
    if (t < MSUB * MSUB) {
      int r = t & (MSUB - 1), c = t >> 4;
      if (c > k && r >= c) shS[r * 17 + c] -= shS[r * 17 + k] * shS[c * 17 + k];
    }
    __syncthreads();
  }
  // rows solve: Qnew L^T = Qold
  if (t < K_) {
    double q[MSUB];
    #pragma unroll
    for (int c = 0; c < MSUB; ++c) {
      double v = shQ[t * MSUB + c];
      for (int p = 0; p < c; ++p) v -= q[p] * shS[c * 17 + p];
      q[c] = v / shS[c * 17 + c];
    }
    #pragma unroll
    for (int c = 0; c < MSUB; ++c) shQ[t * MSUB + c] = q[c];
  }
  __syncthreads();
}

// ---------------- one-block subspace iteration, top-16 eigenpairs ----------
__global__ __launch_bounds__(512) void k_sub(
    const double* __restrict__ rr, const double* __restrict__ invsq,
    float* __restrict__ W1, float* __restrict__ W2)
{
  extern __shared__ double dsm[];
  double* shQ  = dsm;                 // 3056
  double* shZ  = shQ + 3056;          // 3056
  double* shS  = shZ + 3056;          // 272 (16*17)
  double* Ws   = shS + 272;           // 272
  double* inv_s= Ws + 272;            // 192
  double* ev   = inv_s + 192;         // 16
  double* cs_  = ev + 16;             // 8
  double* sn_  = cs_ + 8;             // 8
  int* ipp  = (int*)(sn_ + 8);        // 8
  int* iqq  = ipp + 8;                // 8
  int* perm = iqq + 8;                // 16
  float* tri = (float*)(perm + 16);   // 18336
  const int t = threadIdx.x;

  if (t < K_) inv_s[t] = invsq[t];
  __syncthreads();
  // stage G lower triangle (f32): G_ij = rr_ij * invsq_i * invsq_j
  for (int i = t >> 4; i < K_; i += 32) {
    int base = (i * (i + 1)) / 2;
    double di = inv_s[i];
    for (int j = t & 15; j <= i; j += 16)
      tri[base + j] = (float)(rr[i * LD + j] * di * inv_s[j]);
  }
  __syncthreads();

  // init Q = G[:, 0:16]
  for (int idx = t; idx < K_ * MSUB; idx += 512) {
    int i = idx >> 4, c = idx & 15;
    float g = (i >= c) ? tri[(i * (i + 1)) / 2 + c] : tri[(c * (c + 1)) / 2 + i];
    shQ[idx] = (double)g;
  }
  __syncthreads();

  cholqr(shQ, shS, t);
  for (int it = 0; it < 4; ++it) {
    // copy Q -> Z
    for (int idx = t; idx < K_ * MSUB; idx += 512) shZ[idx] = shQ[idx];
    __syncthreads();
    // Q = G * Z (triangular-packed G), 2 rows x 4 cols per thread.
    if (t < 96 * 4) {
      int i2 = t >> 2, c4 = t & 3;
      int r0 = 2 * i2, r1 = r0 + 1;
      int has1 = (r1 < K_);
      int rb0 = (r0 * (r0 + 1)) >> 1;
      int rb1 = has1 ? ((r1 * (r1 + 1)) >> 1) : rb0;
      int cb0 = c4 * 4;
      double s0a = 0.0, s0b = 0.0, s0c = 0.0, s0d = 0.0;
      double s1a = 0.0, s1b = 0.0, s1c = 0.0, s1d = 0.0;
      #pragma unroll 2
      for (int k = 0; k <= r0; ++k) {
        double g0 = (double)tri[rb0 + k];
        double g1 = (double)tri[rb1 + k];
        double za = shZ[k * MSUB + cb0],     zb = shZ[k * MSUB + cb0 + 1];
        double zc = shZ[k * MSUB + cb0 + 2], zd = shZ[k * MSUB + cb0 + 3];
        s0a += g0 * za; s0b += g0 * zb; s0c += g0 * zc; s0d += g0 * zd;
        s1a += g1 * za; s1b += g1 * zb; s1c += g1 * zc; s1d += g1 * zd;
      }
      if (has1) {
        double g0 = (double)tri[rb1 + r0];   // G[r0][r1] via symmetry
        double g1 = (double)tri[rb1 + r1];
        double za = shZ[r1 * MSUB + cb0],     zb = shZ[r1 * MSUB + cb0 + 1];
        double zc = shZ[r1 * MSUB + cb0 + 2], zd = shZ[r1 * MSUB + cb0 + 3];
        s0a += g0 * za; s0b += g0 * zb; s0c += g0 * zc; s0d += g0 * zd;
        s1a += g1 * za; s1b += g1 * zb; s1c += g1 * zc; s1d += g1 * zd;
      }
      int kk = ((r1 + 1) * (r1 + 2)) >> 1;
      #pragma unroll 2
      for (int k = r1 + 1; k < K_; ++k) {
        double g0 = (double)tri[kk + r0];
        double g1 = (double)tri[kk + r1];
        double za = shZ[k * MSUB + cb0],     zb = shZ[k * MSUB + cb0 + 1];
        double zc = shZ[k * MSUB + cb0 + 2], zd = shZ[k * MSUB + cb0 + 3];
        s0a += g0 * za; s0b += g0 * zb; s0c += g0 * zc; s0d += g0 * zd;
        s1a += g1 * za; s1b += g1 * zb; s1c += g1 * zc; s1d += g1 * zd;
        kk += k + 1;
      }
      shQ[r0 * MSUB + cb0]     = s0a;
      shQ[r0 * MSUB + cb0 + 1] = s0b;
      shQ[r0 * MSUB + cb0 + 2] = s0c;
      shQ[r0 * MSUB + cb0 + 3] = s0d;
      if (has1) {
        shQ[r1 * MSUB + cb0]     = s1a;
        shQ[r1 * MSUB + cb0 + 1] = s1b;
        shQ[r1 * MSUB + cb0 + 2] = s1c;
        shQ[r1 * MSUB + cb0 + 3] = s1d;
      }
    }
    __syncthreads();
    if (it < 3) cholqr(shQ, shS, t);
  }
  // here: shZ = Q_orth, shQ = G*Q_orth.  T = Z^T Q  -> shS
  if (t < MSUB * MSUB) {
    int a = t & 15, b = t >> 4;
    double s = 0.0;
    for (int r = 0; r < K_; ++r) s += shZ[r * MSUB + b] * shQ[r * MSUB + a];
    shS[b * 17 + a] = s;
  }
  // init Ws = I
  if (t < MSUB * 17) Ws[t] = 0.0;
  __syncthreads();
  if (t < MSUB) Ws[t * 17 + t] = 1.0;
  __syncthreads();
  // Jacobi eigensolve of 16x16 T
  for (int sweep = 0; sweep < 6; ++sweep) {
    for (int round = 0; round < 15; ++round) {
      if (t < 8) {
        int ia = (t == 0) ? 0 : (1 + ((t - 1 + round) % 15));
        int ib = 1 + ((14 - t + round) % 15);
        int p = ia < ib ? ia : ib;
        int q = ia < ib ? ib : ia;
        double app = shS[p * 17 + p], aqq = shS[q * 17 + q], apq = shS[p * 17 + q];
        double c = 1.0, s = 0.0;
        if (fabs(apq) > 1e-30 * (fabs(app) + fabs(aqq)) && apq != 0.0) {
          double tau = (aqq - app) / (2.0 * apq);
          double tt = (tau >= 0.0 ? 1.0 : -1.0) / (fabs(tau) + sqrt(1.0 + tau * tau));
          c = 1.0 / sqrt(1.0 + tt * tt); s = tt * c;
        }
        cs_[t] = c; sn_[t] = s; ipp[t] = p; iqq[t] = q;
      }
      __syncthreads();
      if (t < 128) {   // column rotations of T and Ws
        int i = t & 15, mI = t >> 4;
        int p = ipp[mI], q = iqq[mI];
        double c = cs_[mI], s = sn_[mI];
        double u = shS[i * 17 + p], v = shS[i * 17 + q];
        shS[i * 17 + p] = c * u - s * v; shS[i * 17 + q] = s * u + c * v;
        double wu = Ws[i * 17 + p], wv = Ws[i * 17 + q];
        Ws[i * 17 + p] = c * wu - s * wv; Ws[i * 17 + q] = s * wu + c * wv;
      }
      __syncthreads();
      if (t < 128) {   // row rotations of T
        int j = t & 15, mI = t >> 4;
        int p = ipp[mI], q = iqq[mI];
        double c = cs_[mI], s = sn_[mI];
        double u = shS[p * 17 + j], v = shS[q * 17 + j];
        shS[p * 17 + j] = c * u - s * v; shS[q * 17 + j] = s * u + c * v;
      }
      __syncthreads();
    }
  }
  if (t == 0) {
    for (int i = 0; i < MSUB; ++i) { ev[i] = shS[i * 17 + i]; perm[i] = i; }
    for (int i = 0; i < MSUB; ++i) {
      int best = i;
      for (int j = i + 1; j < MSUB; ++j)
        if (ev[perm[j]] > ev[perm[best]]) best = j;
      int tp = perm[i]; perm[i] = perm[best]; perm[best] = tp;
    }
  }
  __syncthreads();
  // E = Q_orth * Ws (sorted); W1[i][c] = invsq_i * E ; W2[c][i] = E * sqrt(om_i)
  for (int idx = t; idx < K_ * MSUB; idx += 512) {
    int i = idx >> 4, c = idx & 15;
    int pc_ = perm[c];
    double e = 0.0;
    #pragma unroll
    for (int p = 0; p < MSUB; ++p) e += shZ[i * MSUB + p] * Ws[p * 17 + pc_];
    W1[i * MSUB + c] = (float)(inv_s[i] * e);
    W2[c * K_ + i]   = (float)(e / inv_s[i]);
  }
}

// ---------------- pc = x * W1 (f32), channel-major output ------------------
__global__ __launch_bounds__(256) void k_pc(const float* __restrict__ x,
                                            const float* __restrict__ W1,
                                            float* __restrict__ pc)
{
  __shared__ float xs[32][192];
  __shared__ float w1s[K_ * MSUB];
  int t = threadIdx.x;
  long n0 = (long)blockIdx.x * 32;
  for (int idx = t; idx < K_ * MSUB; idx += 256) w1s[idx] = W1[idx];
  for (int idx = t; idx < 32 * K_; idx += 256) {
    int row = idx / K_, col = idx - row * K_;
    xs[row][col] = x[(n0 + row) * K_ + col];
  }
  __syncthreads();
  int c = t & 15, nl = t >> 4;         // nl in [0,16)
  float a0 = 0.f, a1 = 0.f;
  for (int k = 0; k < K_; ++k) {
    float w = w1s[k * MSUB + c];
    a0 += xs[nl][k] * w;
    a1 += xs[nl + 16][k] * w;
  }
  __syncthreads();
  float* ts = &xs[0][0];               // reuse as 16x33 transpose buffer
  ts[c * 33 + nl]      = a0;
  ts[c * 33 + nl + 16] = a1;
  __syncthreads();
  for (int idx = t; idx < MSUB * 32; idx += 256) {
    int cc = idx >> 5, nn = idx & 31;
    pc[(size_t)cc * N_ + n0 + nn] = ts[cc * 33 + nn];
  }
}

// ---------------- DWT: vertical analysis pass ------------------------------
__global__ __launch_bounds__(256) void k_dwtv(const float* __restrict__ in,
                                              float* __restrict__ outv, int s)
{
  long gid = (long)blockIdx.x * 256 + threadIdx.x;
  int h = s >> 1;
  long per = (long)h * s;
  if (gid >= MSUB * per) return;
  int ch = (int)(gid / per);
  long rem = gid - (long)ch * per;
  int r = (int)(rem / s);
  int col = (int)(rem - (long)r * s);
  const float* cin = in + (long)ch * s * s;
  float la = 0.f, ld_ = 0.f;
  int base = 2 * r;
  #pragma unroll
  for (int l = 0; l < 10; ++l) {
    int rr_ = base + l; if (rr_ >= s) rr_ -= s;
    float v = cin[(long)rr_ * s + col];
    la += c_lo[l] * v; ld_ += c_hi[l] * v;
  }
  float* cout = outv + (long)ch * s * s;
  cout[(long)r * s + col] = la;
  cout[(long)(h + r) * s + col] = ld_;
}

// ---------------- DWT: horizontal analysis pass ----------------------------
__global__ __launch_bounds__(256) void k_dwth(const float* __restrict__ inv,
                                              float* __restrict__ llout,
                                              float* __restrict__ coef,
                                              int s, long offL, int last)
{
  long gid = (long)blockIdx.x * 256 + threadIdx.x;
  int h = s >> 1;
  long per = (long)s * h;
  if (gid >= MSUB * per) return;
  int ch = (int)(gid / per);
  long rem = gid - (long)ch * per;
  int r = (int)(rem / h);
  int mcol = (int)(rem - (long)r * h);
  const float* row = inv + (long)ch * s * s + (long)r * s;
  float lo = 0.f, hi = 0.f;
  int base = 2 * mcol;
  #pragma unroll
  for (int l = 0; l < 10; ++l) {
    int cc = base + l; if (cc >= s) cc -= s;
    float v = row[cc];
    lo += c_lo[l] * v; hi += c_hi[l] * v;
  }
  float* cslab = coef + (size_t)ch * N_ + offL;
  if (r < h) {
    llout[(size_t)ch * h * h + (long)r * h + mcol] = lo;
    if (last) coef[(size_t)ch * N_ + 147312 + (long)r * h + mcol] = lo;
    cslab[(long)r * h + mcol] = hi;
  } else {
    int rd = r - h;
    cslab[(long)h * h + (long)rd * h + mcol] = lo;
    cslab[(long)2 * h * h + (long)rd * h + mcol] = hi;
  }
}

// ---------------- SURE statistics per channel ------------------------------
__global__ __launch_bounds__(256) void k_stats(const float* __restrict__ coef,
                                               float* __restrict__ stats)
{
  int ch = blockIdx.x;
  int t = threadIdx.x;
  float T2[NT];
  {
    double stop = sqrt(log(147456.0));
    double step = stop / 14.0;
    for (int i = 0; i < NT; ++i) {
      double td = (i == 14) ? stop : (double)i * step;
      float tf = (float)td;
      T2[i] = tf * tf;
    }
  }
  float cn = 0.f, sm[NT], ct[NT];
  #pragma unroll
  for (int i = 0; i < NT; ++i) { sm[i] = 0.f; ct[i] = 0.f; }
  const float* base = coef + (size_t)ch * N_;
  for (int idx = t; idx < N_; idx += 256) {
    float v = base[idx];
    float v2 = v * v;
    cn += v2;
    #pragma unroll
    for (int i = 0; i < NT; ++i) {
      sm[i] += fminf(v2, T2[i]);
      ct[i] += (v2 > T2[i]) ? 1.0f : 0.0f;
    }
  }
  // in-wave shfl reduction (1 barrier total)
  __shared__ float red2[4][32];
  int lane = t & 63, wv = t >> 6;
  for (int a = 0; a < 31; ++a) {
    float val = (a == 0) ? cn : ((a < 16) ? sm[a - 1] : ct[a - 16]);
    #pragma unroll
    for (int off = 32; off > 0; off >>= 1) val += __shfl_down(val, off);
    if (lane == 0) red2[wv][a] = val;
  }
  __syncthreads();
  if (t < 31)
    stats[ch * 31 + t] = red2[0][t] + red2[1][t] + red2[2][t] + red2[3][t];
}

// ---------------- SURE scan + rank -----------------------------------------
__global__ void k_rank(const float* __restrict__ stats,
                       const float* __restrict__ normv, int* __restrict__ rankp)
{
  if (threadIdx.x != 0 || blockIdx.x != 0) return;
  float c_const = *normv - 28164096.0f;
  float acc[NT];
  for (int i = 0; i < NT; ++i) acc[i] = 0.f;
  float minsure[MSUB];
  for (int r = 0; r < MSUB; ++r) {
    float cn = stats[r * 31 + 0];
    float mn = 3.4e38f;
    for (int i = 0; i < NT; ++i) {
      float sure = stats[r * 31 + 1 + i] + 2.0f * stats[r * 31 + 16 + i] - cn;
      float s_r = acc[i] + sure + c_const;
      acc[i] = acc[i] + s_r;
      if (s_r < mn) mn = s_r;
    }
    minsure[r] = mn;
  }
  int rank = -1;
  for (int r = 2; r < MSUB; ++r) {
    if (minsure[r] > minsure[r - 1]) { rank = r; break; }
  }
  if (rank < 0) rank = MSUB - 1;
  *rankp = rank;
}

// ---------------- output: out = sqrt(omega) .* (pc[:, :rank] @ vh) ---------
__global__ __launch_bounds__(256) void k_out(const float* __restrict__ pc,
                                             const float* __restrict__ W2,
                                             const int* __restrict__ rankp,
                                             float* __restrict__ out)
{
  long gid = (long)blockIdx.x * 256 + threadIdx.x;
  int n = (int)(gid / K_);
  int j = (int)(gid - (long)n * K_);
  int rank = *rankp;
  float acc = 0.f;
  for (int c = 0; c < rank; ++c)
    acc += pc[(size_t)c * N_ + n] * W2[c * K_ + j];
  out[gid] = acc;
}

extern "C" void kernel_launch(void* const* d_in, const int* in_sizes, int n_in,
                              void* d_out, int out_size, void* d_ws, size_t ws_size,
                              hipStream_t stream)
{
  if (n_in < 1 || in_sizes[0] != N_ * K_) return;
  const float* x = (const float*)d_in[0];
  float* out = (float*)d_out;
  (void)out_size;

  char* w = (char*)d_ws;
  size_t off = 0;
  auto alloc = [&](size_t bytes) -> char* {
    char* p = w + off;
    off = (off + bytes + 255) & ~(size_t)255;
    return p;
  };
  double* m_    = (double*)alloc(K_ * 8);
  double* rrp   = (double*)alloc((size_t)K_ * K_ * 8);   // atomically-accumulated Gram
  double* rr    = (double*)alloc((size_t)K_ * LD * 8);
  double* Lg    = (double*)alloc((size_t)TRI_N * 8);
  double* rdg   = (double*)alloc(192 * 8);
  double* s2g   = (double*)alloc(192 * 8);
  double* zg    = (double*)alloc(192 * 8);
  double* invsq = (double*)alloc(K_ * 8);
  float*  normv = (float*)alloc(256);
  float*  W1    = (float*)alloc((size_t)K_ * MSUB * 4);
  float*  W2    = (float*)alloc((size_t)MSUB * K_ * 4);
  float*  pc    = (float*)alloc((size_t)MSUB * N_ * 4);
  float*  tmpv  = (float*)alloc((size_t)MSUB * N_ * 4);
  float*  coef  = (float*)alloc((size_t)MSUB * N_ * 4);
  float*  curA  = (float*)alloc((size_t)MSUB * 192 * 192 * 4);
  float*  curB  = (float*)alloc((size_t)MSUB * 96 * 96 * 4);
  float*  stats = (float*)alloc((size_t)MSUB * 31 * 4);
  int*    rankp = (int*)alloc(256);
  if (off > ws_size) return;

  hipMemsetAsync(m_, 0, K_ * sizeof(double), stream);
  hipMemsetAsync(rrp, 0, (size_t)K_ * K_ * sizeof(double), stream);

  hipFuncSetAttribute(reinterpret_cast<const void*>(k_chol),
                      hipFuncAttributeMaxDynamicSharedMemorySize, SMEM_CHOL);
  hipFuncSetAttribute(reinterpret_cast<const void*>(k_csolve),
                      hipFuncAttributeMaxDynamicSharedMemorySize, SMEM_SOLVE);
  hipFuncSetAttribute(reinterpret_cast<const void*>(k_sub),
                      hipFuncAttributeMaxDynamicSharedMemorySize, SMEM2_SZ);

  k_colsum<<<N_ / 512, 256, 0, stream>>>(x, m_);
  k_rr<<<NPAIR * NSPLIT, 256, 0, stream>>>(x, rrp);
  k_reduce<<<(TRI_N + 255) / 256, 256, 0, stream>>>(rrp, rr);
  k_chol<<<1, 512, SMEM_CHOL, stream>>>(rr, Lg, rdg);
  k_csolve<<<K_ + 1, 256, SMEM_SOLVE, stream>>>(Lg, rdg, m_, s2g, zg);
  k_finals<<<1, 256, 0, stream>>>(rr, s2g, zg, invsq, normv);
  k_sub<<<1, 512, SMEM2_SZ, stream>>>(rr, invsq, W1, W2);
  k_pc<<<N_ / 32, 256, 0, stream>>>(x, W1, pc);

  int   sizes[5] = {384, 192, 96, 48, 24};
  long  offs[5]  = {0, 110592, 138240, 145152, 146880};
  float* lls[5]  = {curA, curB, curA, curB, curA};
  const float* curin = pc;
  for (int lev = 0; lev < 5; ++lev) {
    int s = sizes[lev], h = s >> 1;
    long nth = (long)MSUB * h * s;
    k_dwtv<<<(int)((nth + 255) / 256), 256, 0, stream>>>(curin, tmpv, s);
    k_dwth<<<(int)((nth + 255) / 256), 256, 0, stream>>>(tmpv, lls[lev], coef,
                                                         s, offs[lev],
                                                         lev == 4 ? 1 : 0);
    curin = lls[lev];
  }

  k_stats<<<MSUB, 256, 0, stream>>>(coef, stats);
  k_rank<<<1, 64, 0, stream>>>(stats, normv, rankp);
  k_out<<<(N_ * K_) / 256, 256, 0, stream>>>(pc, W2, rankp, out);
}

// Round 8
// 1423.980 us; speedup vs baseline: 1.2121x; 1.0368x over previous
//
#include <hip/hip_runtime.h>
#include <math.h>

#define K_     191
#define LD     192
#define N_     147456
#define MSUB   16
#define NT     15
#define TRI_N  18336   // 191*192/2
#define SMEM_CHOL  ((TRI_N + 1056) * 8)
#define SMEM_SOLVE ((TRI_N + 192 + 192 + 192) * 8)
// k_sub dynamic LDS: 6880 doubles + 32 ints + 18336 floats
#define SMEM2_SZ (6880 * 8 + 32 * 4 + TRI_N * 4)

// k_rr geometry: 64-wide col blocks, 6 pairs, 256 K-splits, 16-row tiles
#define NPAIR  6
#define NSPLIT 256
#define CHUNK  (N_ / NSPLIT)   // 576
#define RSTEP  16

// db5 decomposition filters (pywt convention), f32 as in reference
__constant__ float c_lo[10] = {
  0.003335725285001549f, -0.012580751999015526f, -0.006241490213011705f,
  0.07757149384006515f,  -0.03224486958502952f, -0.24229488706619015f,
  0.13842814590110342f,   0.7243085284385744f,   0.6038292697974729f,
  0.160102397974125f };
__constant__ float c_hi[10] = {
  0.160102397974125f,    -0.6038292697974729f,   0.7243085284385744f,
 -0.13842814590110342f,  -0.24229488706619015f,  0.03224486958502952f,
  0.07757149384006515f,   0.006241490213011705f,-0.012580751999015526f,
 -0.003335725285001549f };

// ---------------- rr = x^T x (f64) + fused column sums, split-K atomics ----
// 64x64 tile per block (pair bi<=bj), 4x4 register sub-tiles, 16-row LDS
// tiles. Staging is lane-contiguous (conflict-free writes, coalesced reads).
// Diagonal pairs alias B to A (skip half the staging) and accumulate the
// column sums of their 64-col slab -> m (replaces the old k_colsum kernel).
__global__ __launch_bounds__(256, 6) void k_rr(const float* __restrict__ x,
                                               double* __restrict__ rrg,
                                               double* __restrict__ m)
{
  __shared__ double Asd[RSTEP][64];
  __shared__ double Bsd[RSTEP][64];   // unused (scratch) for diagonal pairs

  const int bid   = blockIdx.x;
  const int split = bid & (NSPLIT - 1);
  const int pair  = bid >> 8;
  const int BI[6] = {0, 0, 0, 1, 1, 2};
  const int BJ[6] = {0, 1, 2, 1, 2, 2};
  const int bi = BI[pair], bj = BJ[pair];
  const int diag = (bi == bj);
  const int ca = bi * 64, cb = bj * 64;

  const int t  = threadIdx.x;
  const int tx = t & 15, ty = t >> 4;
  const int mycol = t & 63, rowgrp = t >> 6;   // staging/colsum layout
  const long n0 = (long)split * CHUNK;

  double acc[4][4];
  #pragma unroll
  for (int v = 0; v < 4; ++v)
    #pragma unroll
    for (int u = 0; u < 4; ++u) acc[v][u] = 0.0;
  double csum = 0.0;

  for (int r0 = 0; r0 < CHUNK; r0 += RSTEP) {
    // stage: one row of 64 consecutive doubles per wave -> conflict-free
    #pragma unroll
    for (int rr_ = 0; rr_ < RSTEP; rr_ += 4) {
      int row = rr_ + rowgrp;
      long gr = (n0 + r0 + row) * (long)K_;
      int c = ca + mycol;
      double va = (c < K_) ? (double)x[gr + c] : 0.0;
      Asd[row][mycol] = va;
      if (diag) {
        csum += va;
      } else {
        int c2 = cb + mycol;
        Bsd[row][mycol] = (c2 < K_) ? (double)x[gr + c2] : 0.0;
      }
    }
    __syncthreads();
    const double (*Bs)[64] = diag ? Asd : Bsd;
    #pragma unroll 4
    for (int k = 0; k < RSTEP; ++k) {
      double a0 = Asd[k][ty],      a1 = Asd[k][ty + 16];
      double a2 = Asd[k][ty + 32], a3 = Asd[k][ty + 48];
      double b0 = Bs[k][tx],       b1 = Bs[k][tx + 16];
      double b2 = Bs[k][tx + 32],  b3 = Bs[k][tx + 48];
      acc[0][0] += a0 * b0; acc[0][1] += a0 * b1; acc[0][2] += a0 * b2; acc[0][3] += a0 * b3;
      acc[1][0] += a1 * b0; acc[1][1] += a1 * b1; acc[1][2] += a1 * b2; acc[1][3] += a1 * b3;
      acc[2][0] += a2 * b0; acc[2][1] += a2 * b1; acc[2][2] += a2 * b2; acc[2][3] += a2 * b3;
      acc[3][0] += a3 * b0; acc[3][1] += a3 * b1; acc[3][2] += a3 * b2; acc[3][3] += a3 * b3;
    }
    __syncthreads();
  }

  #pragma unroll
  for (int v = 0; v < 4; ++v) {
    int mrow = ca + ty + 16 * v;
    #pragma unroll
    for (int u = 0; u < 4; ++u) {
      int ncol = cb + tx + 16 * u;
      if (mrow < K_ && ncol < K_)
        atomicAdd(&rrg[(size_t)mrow * K_ + ncol], acc[v][u]);
    }
  }

  if (diag) {
    // reduce per-column partial sums (4 row-groups) and add to m
    ((double*)Bsd)[t] = csum;
    __syncthreads();
    if (t < 64) {
      int c = ca + t;
      if (c < K_) {
        double s = ((double*)Bsd)[t] + ((double*)Bsd)[t + 64] +
                   ((double*)Bsd)[t + 128] + ((double*)Bsd)[t + 192];
        atomicAdd(&m[c], s);
      }
    }
  }
}

// ---------------- symmetrize accumulated upper -> rr (full square, LD) -----
__global__ __launch_bounds__(256) void k_reduce(const double* __restrict__ rrg,
                                                double* __restrict__ rr)
{
  int idx = blockIdx.x * 256 + threadIdx.x;   // packed lower-tri index
  if (idx >= TRI_N) return;
  int i = (int)((sqrtf(8.f * (float)idx + 1.f) - 1.f) * 0.5f);
  while ((i + 1) * (i + 2) / 2 <= idx) ++i;
  while (i * (i + 1) / 2 > idx) --i;
  int j = idx - (i * (i + 1)) / 2;            // j <= i
  double s = rrg[(size_t)j * K_ + i];         // valid entries live at (min,max)
  rr[i * LD + j] = s;
  rr[j * LD + i] = s;
}

// ---------------- blocked Cholesky only (exports packed L + recip diag) ----
// 512 threads, round-4 verified structure (no spills).
__global__ __launch_bounds__(512) void k_chol(
    const double* __restrict__ rr, double* __restrict__ Lg,
    double* __restrict__ rdg)
{
  extern __shared__ double smem[];
  double* tri = smem;               // 18336
  double* tmp = smem + TRI_N;       // 1056 scratch (recip diag per panel)
  const int t = threadIdx.x;

  for (int i = t >> 5; i < K_; i += 16) {
    int base = (i * (i + 1)) / 2;
    for (int j = t & 31; j <= i; j += 32) {
      double v = rr[i * LD + j];
      tri[base + j] = (i == j) ? v + 1e-6 : v;
    }
  }
  __syncthreads();

  for (int J = 0; J < 6; ++J) {
    const int j0 = J * 32;
    const int nb = (K_ - j0 < 32) ? (K_ - j0) : 32;   // 32 x5, then 31

    // Phase A: wave 0 factors the diag block in registers (lane = row).
    if (t < 64) {
      const int rl = t & 31;
      double a[32];
      #pragma unroll
      for (int c = 0; c < 32; ++c) {
        int i = j0 + rl;
        a[c] = (c <= rl && rl < nb) ? tri[(i * (i + 1)) / 2 + j0 + c] : 0.0;
      }
      #pragma unroll
      for (int k = 0; k < 32; ++k) {
        double akk = __shfl(a[k], k);
        double piv = sqrt(akk);
        double inv = 1.0 / piv;
        if (t == k) {
          tmp[k] = inv;                          // recip diag for panel solve
          if (j0 + k < K_) rdg[j0 + k] = inv;    // export
        }
        a[k] = (rl == k) ? piv : a[k] * inv;
        #pragma unroll
        for (int c = k + 1; c < 32; ++c) {
          double lck = __shfl(a[k], c);    // L[j0+c][j0+k]
          if (c <= rl) a[c] -= a[k] * lck;
        }
      }
      if (t < 32 && rl < nb) {
        int i = j0 + rl;
        int rb = (i * (i + 1)) / 2 + j0;
        #pragma unroll
        for (int c = 0; c < 32; ++c)
          if (c <= rl) tri[rb + c] = a[c];
      }
    }
    __syncthreads();

    // Phase B: panel solve, one row per thread.
    {
      int p = j0 + 32 + t;
      if (nb == 32 && p < K_) {
        int pb = (p * (p + 1)) / 2 + j0;
        double v[32];
        #pragma unroll
        for (int c = 0; c < 32; ++c) v[c] = tri[pb + c];
        #pragma unroll
        for (int c = 0; c < 32; ++c) {
          double s = v[c];
          #pragma unroll
          for (int q = 0; q < c; ++q) {
            int cc = j0 + c;
            s -= v[q] * tri[(cc * (cc + 1)) / 2 + j0 + q];
          }
          v[c] = s * tmp[c];
        }
        #pragma unroll
        for (int c = 0; c < 32; ++c) tri[pb + c] = v[c];
      }
    }
    __syncthreads();

    // Phase C: trailing update A -= L_panel L_panel^T, 4x4 register tiles.
    {
      int s0 = j0 + 32;
      int n = K_ - s0;
      if (n > 0) {
        int R4 = (n + 3) >> 2;
        int T4 = R4 * (R4 + 1) / 2;
        for (int tile = t; tile < T4; tile += 512) {
          int ti = (int)((sqrtf(8.f * (float)tile + 1.f) - 1.f) * 0.5f);
          while ((ti + 1) * (ti + 2) / 2 <= tile) ++ti;
          while (ti * (ti + 1) / 2 > tile) --ti;
          int tj = tile - ti * (ti + 1) / 2;
          int r0 = s0 + ti * 4, c0 = s0 + tj * 4;
          int rb[4], cb[4];
          #pragma unroll
          for (int u = 0; u < 4; ++u) {
            int r = (r0 + u < K_) ? r0 + u : K_ - 1;
            rb[u] = (r * (r + 1)) / 2;
            int c = (c0 + u < K_) ? c0 + u : K_ - 1;
            cb[u] = (c * (c + 1)) / 2;
          }
          double acc[4][4];
          #pragma unroll
          for (int u = 0; u < 4; ++u)
            #pragma unroll
            for (int v2 = 0; v2 < 4; ++v2) acc[u][v2] = 0.0;
          #pragma unroll 4
          for (int p = 0; p < 32; ++p) {
            double lr[4], lc[4];
            #pragma unroll
            for (int u = 0; u < 4; ++u) {
              lr[u] = tri[rb[u] + j0 + p];
              lc[u] = tri[cb[u] + j0 + p];
            }
            #pragma unroll
            for (int u = 0; u < 4; ++u)
              #pragma unroll
              for (int v2 = 0; v2 < 4; ++v2) acc[u][v2] += lr[u] * lc[v2];
          }
          #pragma unroll
          for (int u = 0; u < 4; ++u) {
            int r = r0 + u;
            if (r < K_) {
              #pragma unroll
              for (int v2 = 0; v2 < 4; ++v2) {
                int c = c0 + v2;
                if (c <= r) tri[rb[u] + c] -= acc[u][v2];
              }
            }
          }
        }
      }
    }
    __syncthreads();
  }

  // export packed L
  for (int idx = t; idx < TRI_N; idx += 512) Lg[idx] = tri[idx];
}

// ---------------- per-column solves of L x = e_i, parallel across blocks ---
// Block i (< K_): forward solve, emit s2[i] = ||column i of L^{-1}||^2.
// Block K_: y = L^{-1} m, then z = L^{-T} y  ->  z = R^{-1} m.
__global__ __launch_bounds__(256) void k_csolve(
    const double* __restrict__ Lg, const double* __restrict__ rdg,
    const double* __restrict__ mg, double* __restrict__ s2g,
    double* __restrict__ zg)
{
  extern __shared__ double ssm[];
  double* Ls   = ssm;               // 18336 (staged from row `start`)
  double* rd_s = Ls + TRI_N;        // 192
  double* m_sh = rd_s + 192;        // 192
  double* ys   = m_sh + 192;        // 192
  const int t = threadIdx.x;
  const int bid = blockIdx.x;

  const int start = (bid < K_) ? (bid * (bid + 1)) / 2 : 0;
  for (int idx = start + t; idx < TRI_N; idx += 256) Ls[idx] = Lg[idx];
  if (t < K_) { rd_s[t] = rdg[t]; m_sh[t] = mg[t]; }
  __syncthreads();

  if (t >= 64) return;              // wave 0 solves; no barriers after
  const int l = t;

  if (bid < K_) {
    const int i = bid;
    double x0 = 0.0, x1 = 0.0, x2 = 0.0;
    {
      double rdi = rd_s[i];
      if ((i & 63) == l) {
        int sl = i >> 6;
        if (sl == 0) x0 = rdi; else if (sl == 1) x1 = rdi; else x2 = rdi;
      }
    }
    for (int r = i + 1; r < K_; ++r) {
      int rb = (r * (r + 1)) >> 1;
      double partial = 0.0;
      { int k = l;       if (k < r) partial += Ls[rb + k] * x0; }
      { int k = l + 64;  if (k < r) partial += Ls[rb + k] * x1; }
      { int k = l + 128; if (k < r) partial += Ls[rb + k] * x2; }
      #pragma unroll
      for (int mm = 32; mm > 0; mm >>= 1) partial += __shfl_xor(partial, mm);
      double val = -partial * rd_s[r];
      if ((r & 63) == l) {
        int sl = r >> 6;
        if (sl == 0) x0 = val; else if (sl == 1) x1 = val; else x2 = val;
      }
    }
    double s2p = x0 * x0 + x1 * x1 + x2 * x2;
    #pragma unroll
    for (int mm = 32; mm > 0; mm >>= 1) s2p += __shfl_xor(s2p, mm);
    if (l == 0) s2g[i] = s2p;
  } else {
    // forward: L y = m
    double y0 = 0.0, y1 = 0.0, y2 = 0.0;
    for (int r = 0; r < K_; ++r) {
      int rb = (r * (r + 1)) >> 1;
      double partial = 0.0;
      { int k = l;       if (k < r) partial += Ls[rb + k] * y0; }
      { int k = l + 64;  if (k < r) partial += Ls[rb + k] * y1; }
      { int k = l + 128; if (k < r) partial += Ls[rb + k] * y2; }
      #pragma unroll
      for (int mm = 32; mm > 0; mm >>= 1) partial += __shfl_xor(partial, mm);
      double val = (m_sh[r] - partial) * rd_s[r];
      if ((r & 63) == l) {
        int sl = r >> 6;
        if (sl == 0) y0 = val; else if (sl == 1) y1 = val; else y2 = val;
      }
      if (l == 0) ys[r] = val;
    }
    // backward: L^T z = y
    double z0 = 0.0, z1 = 0.0, z2 = 0.0;
    for (int r = K_ - 1; r >= 0; --r) {
      double partial = 0.0;
      { int k = l;       if (k > r && k < K_) partial += Ls[((k * (k + 1)) >> 1) + r] * z0; }
      { int k = l + 64;  if (k > r && k < K_) partial += Ls[((k * (k + 1)) >> 1) + r] * z1; }
      { int k = l + 128; if (k > r && k < K_) partial += Ls[((k * (k + 1)) >> 1) + r] * z2; }
      #pragma unroll
      for (int mm = 32; mm > 0; mm >>= 1) partial += __shfl_xor(partial, mm);
      double val = (ys[r] - partial) * rd_s[r];
      if ((r & 63) == l) {
        int sl = r >> 6;
        if (sl == 0) z0 = val; else if (sl == 1) z1 = val; else z2 = val;
      }
      if (l == 0) zg[r] = val;
    }
  }
}

// ---------------- finals: omega, invsq, normv ------------------------------
__global__ __launch_bounds__(256) void k_finals(
    const double* __restrict__ rr, const double* __restrict__ s2g,
    const double* __restrict__ zg, double* __restrict__ invsq,
    float* __restrict__ normv)
{
  __shared__ double tmps[K_];
  const int t = threadIdx.x;
  if (t < K_) {
    double dii = s2g[t];
    double q = 1.0 / dii;
    double sm_ = zg[t] / dii;
    double var = (q - sm_ * sm_ / (double)N_) / (double)(N_ - 1);
    double t1 = sqrt(var) + 1e-30;
    double om = t1 * t1;
    invsq[t] = 1.0 / sqrt(om);
    tmps[t] = rr[t * LD + t] / om;
  }
  __syncthreads();
  if (t < 64) {
    double s = 0.0;
    for (int i = t; i < K_; i += 64) s += tmps[i];
    #pragma unroll
    for (int off = 32; off > 0; off >>= 1) s += __shfl_down(s, off);
    if (t == 0) *normv = (float)s;
  }
}

// ---------------- CholQR helper (operates on shQ K_ x MSUB, shS MSUB x 17) -
__device__ __forceinline__ void cholqr(double* shQ, double* shS, int t)
{
  // S = Q^T Q
  if (t < MSUB * MSUB) {
    int a = t & (MSUB - 1), b = t >> 4;
    double s = 0.0;
    for (int r = 0; r < K_; ++r) s += shQ[r * MSUB + a] * shQ[r * MSUB + b];
    shS[b * 17 + a] = s;
  }
  __syncthreads();
  // Cholesky 16x16 (lower)
  for (int k = 0; k < MSUB; ++k) {
    if (t == 0) shS[k * 17 + k] = sqrt(shS[k * 17 + k]);
    __syncthreads();
    if (t > k && t < MSUB) shS[t * 17 + k] /= shS[k * 17 + k];
    __syncthreads();
    if (t < MSUB * MSUB) {
      int r = t & (MSUB - 1), c = t >> 4;
      if (c > k && r >= c) shS[r * 17 + c] -= shS[r * 17 + k] * shS[c * 17 + k];
    }
    __syncthreads();
  }
  // rows solve: Qnew L^T = Qold
  if (t < K_) {
    double q[MSUB];
    #pragma unroll
    for (int c = 0; c < MSUB; ++c) {
      double v = shQ[t * MSUB + c];
      for (int p = 0; p < c; ++p) v -= q[p] * shS[c * 17 + p];
      q[c] = v / shS[c * 17 + c];
    }
    #pragma unroll
    for (int c = 0; c < MSUB; ++c) shQ[t * MSUB + c] = q[c];
  }
  __syncthreads();
}

// ---------------- one-block subspace iteration, top-16 eigenpairs ----------
__global__ __launch_bounds__(512) void k_sub(
    const double* __restrict__ rr, const double* __restrict__ invsq,
    float* __restrict__ W1, float* __restrict__ W2)
{
  extern __shared__ double dsm[];
  double* shQ  = dsm;                 // 3056
  double* shZ  = shQ + 3056;          // 3056
  double* shS  = shZ + 3056;          // 272 (16*17)
  double* Ws   = shS + 272;           // 272
  double* inv_s= Ws + 272;            // 192
  double* ev   = inv_s + 192;         // 16
  double* cs_  = ev + 16;             // 8
  double* sn_  = cs_ + 8;             // 8
  int* ipp  = (int*)(sn_ + 8);        // 8
  int* iqq  = ipp + 8;                // 8
  int* perm = iqq + 8;                // 16
  float* tri = (float*)(perm + 16);   // 18336
  const int t = threadIdx.x;

  if (t < K_) inv_s[t] = invsq[t];
  __syncthreads();
  // stage G lower triangle (f32): G_ij = rr_ij * invsq_i * invsq_j
  for (int i = t >> 4; i < K_; i += 32) {
    int base = (i * (i + 1)) / 2;
    double di = inv_s[i];
    for (int j = t & 15; j <= i; j += 16)
      tri[base + j] = (float)(rr[i * LD + j] * di * inv_s[j]);
  }
  __syncthreads();

  // init Q = G[:, 0:16]
  for (int idx = t; idx < K_ * MSUB; idx += 512) {
    int i = idx >> 4, c = idx & 15;
    float g = (i >= c) ? tri[(i * (i + 1)) / 2 + c] : tri[(c * (c + 1)) / 2 + i];
    shQ[idx] = (double)g;
  }
  __syncthreads();

  cholqr(shQ, shS, t);
  for (int it = 0; it < 4; ++it) {
    // copy Q -> Z
    for (int idx = t; idx < K_ * MSUB; idx += 512) shZ[idx] = shQ[idx];
    __syncthreads();
    // Q = G * Z (triangular-packed G), 2 rows x 4 cols per thread.
    if (t < 96 * 4) {
      int i2 = t >> 2, c4 = t & 3;
      int r0 = 2 * i2, r1 = r0 + 1;
      int has1 = (r1 < K_);
      int rb0 = (r0 * (r0 + 1)) >> 1;
      int rb1 = has1 ? ((r1 * (r1 + 1)) >> 1) : rb0;
      int cb0 = c4 * 4;
      double s0a = 0.0, s0b = 0.0, s0c = 0.0, s0d = 0.0;
      double s1a = 0.0, s1b = 0.0, s1c = 0.0, s1d = 0.0;
      #pragma unroll 2
      for (int k = 0; k <= r0; ++k) {
        double g0 = (double)tri[rb0 + k];
        double g1 = (double)tri[rb1 + k];
        double za = shZ[k * MSUB + cb0],     zb = shZ[k * MSUB + cb0 + 1];
        double zc = shZ[k * MSUB + cb0 + 2], zd = shZ[k * MSUB + cb0 + 3];
        s0a += g0 * za; s0b += g0 * zb; s0c += g0 * zc; s0d += g0 * zd;
        s1a += g1 * za; s1b += g1 * zb; s1c += g1 * zc; s1d += g1 * zd;
      }
      if (has1) {
        double g0 = (double)tri[rb1 + r0];   // G[r0][r1] via symmetry
        double g1 = (double)tri[rb1 + r1];
        double za = shZ[r1 * MSUB + cb0],     zb = shZ[r1 * MSUB + cb0 + 1];
        double zc = shZ[r1 * MSUB + cb0 + 2], zd = shZ[r1 * MSUB + cb0 + 3];
        s0a += g0 * za; s0b += g0 * zb; s0c += g0 * zc; s0d += g0 * zd;
        s1a += g1 * za; s1b += g1 * zb; s1c += g1 * zc; s1d += g1 * zd;
      }
      int kk = ((r1 + 1) * (r1 + 2)) >> 1;
      #pragma unroll 2
      for (int k = r1 + 1; k < K_; ++k) {
        double g0 = (double)tri[kk + r0];
        double g1 = (double)tri[kk + r1];
        double za = shZ[k * MSUB + cb0],     zb = shZ[k * MSUB + cb0 + 1];
        double zc = shZ[k * MSUB + cb0 + 2], zd = shZ[k * MSUB + cb0 + 3];
        s0a += g0 * za; s0b += g0 * zb; s0c += g0 * zc; s0d += g0 * zd;
        s1a += g1 * za; s1b += g1 * zb; s1c += g1 * zc; s1d += g1 * zd;
        kk += k + 1;
      }
      shQ[r0 * MSUB + cb0]     = s0a;
      shQ[r0 * MSUB + cb0 + 1] = s0b;
      shQ[r0 * MSUB + cb0 + 2] = s0c;
      shQ[r0 * MSUB + cb0 + 3] = s0d;
      if (has1) {
        shQ[r1 * MSUB + cb0]     = s1a;
        shQ[r1 * MSUB + cb0 + 1] = s1b;
        shQ[r1 * MSUB + cb0 + 2] = s1c;
        shQ[r1 * MSUB + cb0 + 3] = s1d;
      }
    }
    __syncthreads();
    if (it < 3) cholqr(shQ, shS, t);
  }
  // here: shZ = Q_orth, shQ = G*Q_orth.  T = Z^T Q  -> shS
  if (t < MSUB * MSUB) {
    int a = t & 15, b = t >> 4;
    double s = 0.0;
    for (int r = 0; r < K_; ++r) s += shZ[r * MSUB + b] * shQ[r * MSUB + a];
    shS[b * 17 + a] = s;
  }
  // init Ws = I
  if (t < MSUB * 17) Ws[t] = 0.0;
  __syncthreads();
  if (t < MSUB) Ws[t * 17 + t] = 1.0;
  __syncthreads();
  // Jacobi eigensolve of 16x16 T
  for (int sweep = 0; sweep < 6; ++sweep) {
    for (int round = 0; round < 15; ++round) {
      if (t < 8) {
        int ia = (t == 0) ? 0 : (1 + ((t - 1 + round) % 15));
        int ib = 1 + ((14 - t + round) % 15);
        int p = ia < ib ? ia : ib;
        int q = ia < ib ? ib : ia;
        double app = shS[p * 17 + p], aqq = shS[q * 17 + q], apq = shS[p * 17 + q];
        double c = 1.0, s = 0.0;
        if (fabs(apq) > 1e-30 * (fabs(app) + fabs(aqq)) && apq != 0.0) {
          double tau = (aqq - app) / (2.0 * apq);
          double tt = (tau >= 0.0 ? 1.0 : -1.0) / (fabs(tau) + sqrt(1.0 + tau * tau));
          c = 1.0 / sqrt(1.0 + tt * tt); s = tt * c;
        }
        cs_[t] = c; sn_[t] = s; ipp[t] = p; iqq[t] = q;
      }
      __syncthreads();
      if (t < 128) {   // column rotations of T and Ws
        int i = t & 15, mI = t >> 4;
        int p = ipp[mI], q = iqq[mI];
        double c = cs_[mI], s = sn_[mI];
        double u = shS[i * 17 + p], v = shS[i * 17 + q];
        shS[i * 17 + p] = c * u - s * v; shS[i * 17 + q] = s * u + c * v;
        double wu = Ws[i * 17 + p], wv = Ws[i * 17 + q];
        Ws[i * 17 + p] = c * wu - s * wv; Ws[i * 17 + q] = s * wu + c * wv;
      }
      __syncthreads();
      if (t < 128) {   // row rotations of T
        int j = t & 15, mI = t >> 4;
        int p = ipp[mI], q = iqq[mI];
        double c = cs_[mI], s = sn_[mI];
        double u = shS[p * 17 + j], v = shS[q * 17 + j];
        shS[p * 17 + j] = c * u - s * v; shS[q * 17 + j] = s * u + c * v;
      }
      __syncthreads();
    }
  }
  if (t == 0) {
    for (int i = 0; i < MSUB; ++i) { ev[i] = shS[i * 17 + i]; perm[i] = i; }
    for (int i = 0; i < MSUB; ++i) {
      int best = i;
      for (int j = i + 1; j < MSUB; ++j)
        if (ev[perm[j]] > ev[perm[best]]) best = j;
      int tp = perm[i]; perm[i] = perm[best]; perm[best] = tp;
    }
  }
  __syncthreads();
  // E = Q_orth * Ws (sorted); W1[i][c] = invsq_i * E ; W2[c][i] = E * sqrt(om_i)
  for (int idx = t; idx < K_ * MSUB; idx += 512) {
    int i = idx >> 4, c = idx & 15;
    int pc_ = perm[c];
    double e = 0.0;
    #pragma unroll
    for (int p = 0; p < MSUB; ++p) e += shZ[i * MSUB + p] * Ws[p * 17 + pc_];
    W1[i * MSUB + c] = (float)(inv_s[i] * e);
    W2[c * K_ + i]   = (float)(e / inv_s[i]);
  }
}

// ---------------- pc = x * W1 (f32), channel-major output ------------------
__global__ __launch_bounds__(256) void k_pc(const float* __restrict__ x,
                                            const float* __restrict__ W1,
                                            float* __restrict__ pc)
{
  __shared__ float xs[32][192];
  __shared__ float w1s[K_ * MSUB];
  int t = threadIdx.x;
  long n0 = (long)blockIdx.x * 32;
  for (int idx = t; idx < K_ * MSUB; idx += 256) w1s[idx] = W1[idx];
  for (int idx = t; idx < 32 * K_; idx += 256) {
    int row = idx / K_, col = idx - row * K_;
    xs[row][col] = x[(n0 + row) * K_ + col];
  }
  __syncthreads();
  int c = t & 15, nl = t >> 4;         // nl in [0,16)
  float a0 = 0.f, a1 = 0.f;
  for (int k = 0; k < K_; ++k) {
    float w = w1s[k * MSUB + c];
    a0 += xs[nl][k] * w;
    a1 += xs[nl + 16][k] * w;
  }
  __syncthreads();
  float* ts = &xs[0][0];               // reuse as 16x33 transpose buffer
  ts[c * 33 + nl]      = a0;
  ts[c * 33 + nl + 16] = a1;
  __syncthreads();
  for (int idx = t; idx < MSUB * 32; idx += 256) {
    int cc = idx >> 5, nn = idx & 31;
    pc[(size_t)cc * N_ + n0 + nn] = ts[cc * 33 + nn];
  }
}

// ---------------- DWT: vertical analysis pass ------------------------------
__global__ __launch_bounds__(256) void k_dwtv(const float* __restrict__ in,
                                              float* __restrict__ outv, int s)
{
  long gid = (long)blockIdx.x * 256 + threadIdx.x;
  int h = s >> 1;
  long per = (long)h * s;
  if (gid >= MSUB * per) return;
  int ch = (int)(gid / per);
  long rem = gid - (long)ch * per;
  int r = (int)(rem / s);
  int col = (int)(rem - (long)r * s);
  const float* cin = in + (long)ch * s * s;
  float la = 0.f, ld_ = 0.f;
  int base = 2 * r;
  #pragma unroll
  for (int l = 0; l < 10; ++l) {
    int rr_ = base + l; if (rr_ >= s) rr_ -= s;
    float v = cin[(long)rr_ * s + col];
    la += c_lo[l] * v; ld_ += c_hi[l] * v;
  }
  float* cout = outv + (long)ch * s * s;
  cout[(long)r * s + col] = la;
  cout[(long)(h + r) * s + col] = ld_;
}

// ---------------- DWT: horizontal analysis pass ----------------------------
__global__ __launch_bounds__(256) void k_dwth(const float* __restrict__ inv,
                                              float* __restrict__ llout,
                                              float* __restrict__ coef,
                                              int s, long offL, int last)
{
  long gid = (long)blockIdx.x * 256 + threadIdx.x;
  int h = s >> 1;
  long per = (long)s * h;
  if (gid >= MSUB * per) return;
  int ch = (int)(gid / per);
  long rem = gid - (long)ch * per;
  int r = (int)(rem / h);
  int mcol = (int)(rem - (long)r * h);
  const float* row = inv + (long)ch * s * s + (long)r * s;
  float lo = 0.f, hi = 0.f;
  int base = 2 * mcol;
  #pragma unroll
  for (int l = 0; l < 10; ++l) {
    int cc = base + l; if (cc >= s) cc -= s;
    float v = row[cc];
    lo += c_lo[l] * v; hi += c_hi[l] * v;
  }
  float* cslab = coef + (size_t)ch * N_ + offL;
  if (r < h) {
    llout[(size_t)ch * h * h + (long)r * h + mcol] = lo;
    if (last) coef[(size_t)ch * N_ + 147312 + (long)r * h + mcol] = lo;
    cslab[(long)r * h + mcol] = hi;
  } else {
    int rd = r - h;
    cslab[(long)h * h + (long)rd * h + mcol] = lo;
    cslab[(long)2 * h * h + (long)rd * h + mcol] = hi;
  }
}

// ---------------- SURE statistics per channel ------------------------------
__global__ __launch_bounds__(256) void k_stats(const float* __restrict__ coef,
                                               float* __restrict__ stats)
{
  int ch = blockIdx.x;
  int t = threadIdx.x;
  float T2[NT];
  {
    double stop = sqrt(log(147456.0));
    double step = stop / 14.0;
    for (int i = 0; i < NT; ++i) {
      double td = (i == 14) ? stop : (double)i * step;
      float tf = (float)td;
      T2[i] = tf * tf;
    }
  }
  float cn = 0.f, sm[NT], ct[NT];
  #pragma unroll
  for (int i = 0; i < NT; ++i) { sm[i] = 0.f; ct[i] = 0.f; }
  const float* base = coef + (size_t)ch * N_;
  for (int idx = t; idx < N_; idx += 256) {
    float v = base[idx];
    float v2 = v * v;
    cn += v2;
    #pragma unroll
    for (int i = 0; i < NT; ++i) {
      sm[i] += fminf(v2, T2[i]);
      ct[i] += (v2 > T2[i]) ? 1.0f : 0.0f;
    }
  }
  // in-wave shfl reduction (1 barrier total)
  __shared__ float red2[4][32];
  int lane = t & 63, wv = t >> 6;
  for (int a = 0; a < 31; ++a) {
    float val = (a == 0) ? cn : ((a < 16) ? sm[a - 1] : ct[a - 16]);
    #pragma unroll
    for (int off = 32; off > 0; off >>= 1) val += __shfl_down(val, off);
    if (lane == 0) red2[wv][a] = val;
  }
  __syncthreads();
  if (t < 31)
    stats[ch * 31 + t] = red2[0][t] + red2[1][t] + red2[2][t] + red2[3][t];
}

// ---------------- SURE scan + rank -----------------------------------------
__global__ void k_rank(const float* __restrict__ stats,
                       const float* __restrict__ normv, int* __restrict__ rankp)
{
  if (threadIdx.x != 0 || blockIdx.x != 0) return;
  float c_const = *normv - 28164096.0f;
  float acc[NT];
  for (int i = 0; i < NT; ++i) acc[i] = 0.f;
  float minsure[MSUB];
  for (int r = 0; r < MSUB; ++r) {
    float cn = stats[r * 31 + 0];
    float mn = 3.4e38f;
    for (int i = 0; i < NT; ++i) {
      float sure = stats[r * 31 + 1 + i] + 2.0f * stats[r * 31 + 16 + i] - cn;
      float s_r = acc[i] + sure + c_const;
      acc[i] = acc[i] + s_r;
      if (s_r < mn) mn = s_r;
    }
    minsure[r] = mn;
  }
  int rank = -1;
  for (int r = 2; r < MSUB; ++r) {
    if (minsure[r] > minsure[r - 1]) { rank = r; break; }
  }
  if (rank < 0) rank = MSUB - 1;
  *rankp = rank;
}

// ---------------- output: out = sqrt(omega) .* (pc[:, :rank] @ vh) ---------
__global__ __launch_bounds__(256) void k_out(const float* __restrict__ pc,
                                             const float* __restrict__ W2,
                                             const int* __restrict__ rankp,
                                             float* __restrict__ out)
{
  long gid = (long)blockIdx.x * 256 + threadIdx.x;
  int n = (int)(gid / K_);
  int j = (int)(gid - (long)n * K_);
  int rank = *rankp;
  float acc = 0.f;
  for (int c = 0; c < rank; ++c)
    acc += pc[(size_t)c * N_ + n] * W2[c * K_ + j];
  out[gid] = acc;
}

extern "C" void kernel_launch(void* const* d_in, const int* in_sizes, int n_in,
                              void* d_out, int out_size, void* d_ws, size_t ws_size,
                              hipStream_t stream)
{
  if (n_in < 1 || in_sizes[0] != N_ * K_) return;
  const float* x = (const float*)d_in[0];
  float* out = (float*)d_out;
  (void)out_size;

  char* w = (char*)d_ws;
  size_t off = 0;
  auto alloc = [&](size_t bytes) -> char* {
    char* p = w + off;
    off = (off + bytes + 255) & ~(size_t)255;
    return p;
  };
  double* m_    = (double*)alloc(K_ * 8);
  double* rrp   = (double*)alloc((size_t)K_ * K_ * 8);   // atomically-accumulated Gram
  double* rr    = (double*)alloc((size_t)K_ * LD * 8);
  double* Lg    = (double*)alloc((size_t)TRI_N * 8);
  double* rdg   = (double*)alloc(192 * 8);
  double* s2g   = (double*)alloc(192 * 8);
  double* zg    = (double*)alloc(192 * 8);
  double* invsq = (double*)alloc(K_ * 8);
  float*  normv = (float*)alloc(256);
  float*  W1    = (float*)alloc((size_t)K_ * MSUB * 4);
  float*  W2    = (float*)alloc((size_t)MSUB * K_ * 4);
  float*  pc    = (float*)alloc((size_t)MSUB * N_ * 4);
  float*  tmpv  = (float*)alloc((size_t)MSUB * N_ * 4);
  float*  coef  = (float*)alloc((size_t)MSUB * N_ * 4);
  float*  curA  = (float*)alloc((size_t)MSUB * 192 * 192 * 4);
  float*  curB  = (float*)alloc((size_t)MSUB * 96 * 96 * 4);
  float*  stats = (float*)alloc((size_t)MSUB * 31 * 4);
  int*    rankp = (int*)alloc(256);
  if (off > ws_size) return;

  hipMemsetAsync(m_, 0, K_ * sizeof(double), stream);
  hipMemsetAsync(rrp, 0, (size_t)K_ * K_ * sizeof(double), stream);

  hipFuncSetAttribute(reinterpret_cast<const void*>(k_chol),
                      hipFuncAttributeMaxDynamicSharedMemorySize, SMEM_CHOL);
  hipFuncSetAttribute(reinterpret_cast<const void*>(k_csolve),
                      hipFuncAttributeMaxDynamicSharedMemorySize, SMEM_SOLVE);
  hipFuncSetAttribute(reinterpret_cast<const void*>(k_sub),
                      hipFuncAttributeMaxDynamicSharedMemorySize, SMEM2_SZ);

  k_rr<<<NPAIR * NSPLIT, 256, 0, stream>>>(x, rrp, m_);
  k_reduce<<<(TRI_N + 255) / 256, 256, 0, stream>>>(rrp, rr);
  k_chol<<<1, 512, SMEM_CHOL, stream>>>(rr, Lg, rdg);
  k_csolve<<<K_ + 1, 256, SMEM_SOLVE, stream>>>(Lg, rdg, m_, s2g, zg);
  k_finals<<<1, 256, 0, stream>>>(rr, s2g, zg, invsq, normv);
  k_sub<<<1, 512, SMEM2_SZ, stream>>>(rr, invsq, W1, W2);
  k_pc<<<N_ / 32, 256, 0, stream>>>(x, W1, pc);

  int   sizes[5] = {384, 192, 96, 48, 24};
  long  offs[5]  = {0, 110592, 138240, 145152, 146880};
  float* lls[5]  = {curA, curB, curA, curB, curA};
  const float* curin = pc;
  for (int lev = 0; lev < 5; ++lev) {
    int s = sizes[lev], h = s >> 1;
    long nth = (long)MSUB * h * s;
    k_dwtv<<<(int)((nth + 255) / 256), 256, 0, stream>>>(curin, tmpv, s);
    k_dwth<<<(int)((nth + 255) / 256), 256, 0, stream>>>(tmpv, lls[lev], coef,
                                                         s, offs[lev],
                                                         lev == 4 ? 1 : 0);
    curin = lls[lev];
  }

  k_stats<<<MSUB, 256, 0, stream>>>(coef, stats);
  k_rank<<<1, 64, 0, stream>>>(stats, normv, rankp);
  k_out<<<(N_ * K_) / 256, 256, 0, stream>>>(pc, W2, rankp, out);
}

// Round 9
// 1386.623 us; speedup vs baseline: 1.2447x; 1.0269x over previous
//
#include <hip/hip_runtime.h>
#include <math.h>

#define K_     191
#define LD     192
#define N_     147456
#define MSUB   16
#define NT     15
#define TRI_N  18336   // 191*192/2
#define SMEM_CHOL  ((TRI_N + 1056) * 8)
#define SMEM_SOLVE ((TRI_N + 192 + 192 + 192) * 8)
// k_sub dynamic LDS: 6880 doubles + 32 ints + 18336 floats
#define SMEM2_SZ (6880 * 8 + 32 * 4 + TRI_N * 4)

// k_rr geometry: 64-wide col blocks, 6 pairs, 256 K-splits, 16-row tiles
#define NPAIR  6
#define NSPLIT 256
#define CHUNK  (N_ / NSPLIT)   // 576
#define RSTEP  16

// db5 decomposition filters (pywt convention), f32 as in reference
__constant__ float c_lo[10] = {
  0.003335725285001549f, -0.012580751999015526f, -0.006241490213011705f,
  0.07757149384006515f,  -0.03224486958502952f, -0.24229488706619015f,
  0.13842814590110342f,   0.7243085284385744f,   0.6038292697974729f,
  0.160102397974125f };
__constant__ float c_hi[10] = {
  0.160102397974125f,    -0.6038292697974729f,   0.7243085284385744f,
 -0.13842814590110342f,  -0.24229488706619015f,  0.03224486958502952f,
  0.07757149384006515f,   0.006241490213011705f,-0.012580751999015526f,
 -0.003335725285001549f };

// ---------------- rr = x^T x (f64) + fused column sums, split-K atomics ----
// 64x64 tile per block (pair bi<=bj), 4x4 register sub-tiles. x staged as
// f32 (halves LDS bandwidth; f32->f64 cvt at read is exact => rr identical),
// double-buffered (prefetch tile t+1 to registers during compute of t).
// Diagonal pairs alias B to A and fold column sums -> m.
__global__ __launch_bounds__(256, 6) void k_rr(const float* __restrict__ x,
                                               double* __restrict__ rrg,
                                               double* __restrict__ m)
{
  __shared__ float Asf[2][RSTEP][64];
  __shared__ float Bsf[2][RSTEP][64];   // unused (scratch) for diagonal pairs

  const int bid   = blockIdx.x;
  const int split = bid & (NSPLIT - 1);
  const int pair  = bid >> 8;
  const int BI[6] = {0, 0, 0, 1, 1, 2};
  const int BJ[6] = {0, 1, 2, 1, 2, 2};
  const int bi = BI[pair], bj = BJ[pair];
  const int diag = (bi == bj);
  const int ca = bi * 64, cb = bj * 64;

  const int t  = threadIdx.x;
  const int tx = t & 15, ty = t >> 4;
  const int mycol = t & 63, rowgrp = t >> 6;   // staging layout
  const long n0 = (long)split * CHUNK;

  double acc[4][4];
  #pragma unroll
  for (int v = 0; v < 4; ++v)
    #pragma unroll
    for (int u = 0; u < 4; ++u) acc[v][u] = 0.0;
  double csum = 0.0;

  float ra[4], rbv[4];
  const int cA = ca + mycol, cB = cb + mycol;
  const bool okA = (cA < K_), okB = (cB < K_);

  // load tile at row offset r0 into registers (coalesced f32), fold csum
  auto LOADT = [&](int r0) {
    #pragma unroll
    for (int i = 0; i < 4; ++i) {
      int row = i * 4 + rowgrp;
      long gr = (n0 + r0 + row) * (long)K_;
      float va = okA ? x[gr + cA] : 0.f;
      ra[i] = va;
      if (diag) csum += (double)va;
      else      rbv[i] = okB ? x[gr + cB] : 0.f;
    }
  };
  auto WRITET = [&](int buf) {
    #pragma unroll
    for (int i = 0; i < 4; ++i) {
      int row = i * 4 + rowgrp;
      Asf[buf][row][mycol] = ra[i];
      if (!diag) Bsf[buf][row][mycol] = rbv[i];
    }
  };

  LOADT(0);
  WRITET(0);
  __syncthreads();

  int cur = 0;
  for (int r0 = 0; r0 < CHUNK; r0 += RSTEP) {
    const bool hasnext = (r0 + RSTEP < CHUNK);
    if (hasnext) LOADT(r0 + RSTEP);        // global loads in flight
    const float (*As)[64] = Asf[cur];
    const float (*Bs)[64] = diag ? Asf[cur] : Bsf[cur];
    #pragma unroll 4
    for (int k = 0; k < RSTEP; ++k) {
      double a0 = (double)As[k][ty],      a1 = (double)As[k][ty + 16];
      double a2 = (double)As[k][ty + 32], a3 = (double)As[k][ty + 48];
      double b0 = (double)Bs[k][tx],      b1 = (double)Bs[k][tx + 16];
      double b2 = (double)Bs[k][tx + 32], b3 = (double)Bs[k][tx + 48];
      acc[0][0] += a0 * b0; acc[0][1] += a0 * b1; acc[0][2] += a0 * b2; acc[0][3] += a0 * b3;
      acc[1][0] += a1 * b0; acc[1][1] += a1 * b1; acc[1][2] += a1 * b2; acc[1][3] += a1 * b3;
      acc[2][0] += a2 * b0; acc[2][1] += a2 * b1; acc[2][2] += a2 * b2; acc[2][3] += a2 * b3;
      acc[3][0] += a3 * b0; acc[3][1] += a3 * b1; acc[3][2] += a3 * b2; acc[3][3] += a3 * b3;
    }
    if (hasnext) WRITET(cur ^ 1);          // other buffer: no read conflict
    __syncthreads();
    cur ^= 1;
  }

  #pragma unroll
  for (int v = 0; v < 4; ++v) {
    int mrow = ca + ty + 16 * v;
    #pragma unroll
    for (int u = 0; u < 4; ++u) {
      int ncol = cb + tx + 16 * u;
      if (mrow < K_ && ncol < K_)
        atomicAdd(&rrg[(size_t)mrow * K_ + ncol], acc[v][u]);
    }
  }

  if (diag) {
    // reduce per-column partial sums (4 row-groups) via Bsf scratch
    double* sc = (double*)Bsf;
    sc[t] = csum;
    __syncthreads();
    if (t < 64) {
      int c = ca + t;
      if (c < K_) {
        double s = sc[t] + sc[t + 64] + sc[t + 128] + sc[t + 192];
        atomicAdd(&m[c], s);
      }
    }
  }
}

// ---------------- symmetrize accumulated upper -> rr (full square, LD) -----
__global__ __launch_bounds__(256) void k_reduce(const double* __restrict__ rrg,
                                                double* __restrict__ rr)
{
  int idx = blockIdx.x * 256 + threadIdx.x;   // packed lower-tri index
  if (idx >= TRI_N) return;
  int i = (int)((sqrtf(8.f * (float)idx + 1.f) - 1.f) * 0.5f);
  while ((i + 1) * (i + 2) / 2 <= idx) ++i;
  while (i * (i + 1) / 2 > idx) --i;
  int j = idx - (i * (i + 1)) / 2;            // j <= i
  double s = rrg[(size_t)j * K_ + i];         // valid entries live at (min,max)
  rr[i * LD + j] = s;
  rr[j * LD + i] = s;
}

// ---------------- blocked Cholesky only (exports packed L + recip diag) ----
// 512 threads, round-4 verified structure (no spills).
__global__ __launch_bounds__(512) void k_chol(
    const double* __restrict__ rr, double* __restrict__ Lg,
    double* __restrict__ rdg)
{
  extern __shared__ double smem[];
  double* tri = smem;               // 18336
  double* tmp = smem + TRI_N;       // 1056 scratch (recip diag per panel)
  const int t = threadIdx.x;

  for (int i = t >> 5; i < K_; i += 16) {
    int base = (i * (i + 1)) / 2;
    for (int j = t & 31; j <= i; j += 32) {
      double v = rr[i * LD + j];
      tri[base + j] = (i == j) ? v + 1e-6 : v;
    }
  }
  __syncthreads();

  for (int J = 0; J < 6; ++J) {
    const int j0 = J * 32;
    const int nb = (K_ - j0 < 32) ? (K_ - j0) : 32;   // 32 x5, then 31

    // Phase A: wave 0 factors the diag block in registers (lane = row).
    if (t < 64) {
      const int rl = t & 31;
      double a[32];
      #pragma unroll
      for (int c = 0; c < 32; ++c) {
        int i = j0 + rl;
        a[c] = (c <= rl && rl < nb) ? tri[(i * (i + 1)) / 2 + j0 + c] : 0.0;
      }
      #pragma unroll
      for (int k = 0; k < 32; ++k) {
        double akk = __shfl(a[k], k);
        double piv = sqrt(akk);
        double inv = 1.0 / piv;
        if (t == k) {
          tmp[k] = inv;                          // recip diag for panel solve
          if (j0 + k < K_) rdg[j0 + k] = inv;    // export
        }
        a[k] = (rl == k) ? piv : a[k] * inv;
        #pragma unroll
        for (int c = k + 1; c < 32; ++c) {
          double lck = __shfl(a[k], c);    // L[j0+c][j0+k]
          if (c <= rl) a[c] -= a[k] * lck;
        }
      }
      if (t < 32 && rl < nb) {
        int i = j0 + rl;
        int rb = (i * (i + 1)) / 2 + j0;
        #pragma unroll
        for (int c = 0; c < 32; ++c)
          if (c <= rl) tri[rb + c] = a[c];
      }
    }
    __syncthreads();

    // Phase B: panel solve, one row per thread.
    {
      int p = j0 + 32 + t;
      if (nb == 32 && p < K_) {
        int pb = (p * (p + 1)) / 2 + j0;
        double v[32];
        #pragma unroll
        for (int c = 0; c < 32; ++c) v[c] = tri[pb + c];
        #pragma unroll
        for (int c = 0; c < 32; ++c) {
          double s = v[c];
          #pragma unroll
          for (int q = 0; q < c; ++q) {
            int cc = j0 + c;
            s -= v[q] * tri[(cc * (cc + 1)) / 2 + j0 + q];
          }
          v[c] = s * tmp[c];
        }
        #pragma unroll
        for (int c = 0; c < 32; ++c) tri[pb + c] = v[c];
      }
    }
    __syncthreads();

    // Phase C: trailing update A -= L_panel L_panel^T, 4x4 register tiles.
    {
      int s0 = j0 + 32;
      int n = K_ - s0;
      if (n > 0) {
        int R4 = (n + 3) >> 2;
        int T4 = R4 * (R4 + 1) / 2;
        for (int tile = t; tile < T4; tile += 512) {
          int ti = (int)((sqrtf(8.f * (float)tile + 1.f) - 1.f) * 0.5f);
          while ((ti + 1) * (ti + 2) / 2 <= tile) ++ti;
          while (ti * (ti + 1) / 2 > tile) --ti;
          int tj = tile - ti * (ti + 1) / 2;
          int r0 = s0 + ti * 4, c0 = s0 + tj * 4;
          int rb[4], cb[4];
          #pragma unroll
          for (int u = 0; u < 4; ++u) {
            int r = (r0 + u < K_) ? r0 + u : K_ - 1;
            rb[u] = (r * (r + 1)) / 2;
            int c = (c0 + u < K_) ? c0 + u : K_ - 1;
            cb[u] = (c * (c + 1)) / 2;
          }
          double acc[4][4];
          #pragma unroll
          for (int u = 0; u < 4; ++u)
            #pragma unroll
            for (int v2 = 0; v2 < 4; ++v2) acc[u][v2] = 0.0;
          #pragma unroll 4
          for (int p = 0; p < 32; ++p) {
            double lr[4], lc[4];
            #pragma unroll
            for (int u = 0; u < 4; ++u) {
              lr[u] = tri[rb[u] + j0 + p];
              lc[u] = tri[cb[u] + j0 + p];
            }
            #pragma unroll
            for (int u = 0; u < 4; ++u)
              #pragma unroll
              for (int v2 = 0; v2 < 4; ++v2) acc[u][v2] += lr[u] * lc[v2];
          }
          #pragma unroll
          for (int u = 0; u < 4; ++u) {
            int r = r0 + u;
            if (r < K_) {
              #pragma unroll
              for (int v2 = 0; v2 < 4; ++v2) {
                int c = c0 + v2;
                if (c <= r) tri[rb[u] + c] -= acc[u][v2];
              }
            }
          }
        }
      }
    }
    __syncthreads();
  }

  // export packed L
  for (int idx = t; idx < TRI_N; idx += 512) Lg[idx] = tri[idx];
}

// ---------------- per-column solves of L x = e_i, parallel across blocks ---
// Block i (< K_): forward solve, emit s2[i] = ||column i of L^{-1}||^2.
// Block K_: y = L^{-1} m, then z = L^{-T} y  ->  z = R^{-1} m.
__global__ __launch_bounds__(256) void k_csolve(
    const double* __restrict__ Lg, const double* __restrict__ rdg,
    const double* __restrict__ mg, double* __restrict__ s2g,
    double* __restrict__ zg)
{
  extern __shared__ double ssm[];
  double* Ls   = ssm;               // 18336 (staged from row `start`)
  double* rd_s = Ls + TRI_N;        // 192
  double* m_sh = rd_s + 192;        // 192
  double* ys   = m_sh + 192;        // 192
  const int t = threadIdx.x;
  const int bid = blockIdx.x;

  const int start = (bid < K_) ? (bid * (bid + 1)) / 2 : 0;
  for (int idx = start + t; idx < TRI_N; idx += 256) Ls[idx] = Lg[idx];
  if (t < K_) { rd_s[t] = rdg[t]; m_sh[t] = mg[t]; }
  __syncthreads();

  if (t >= 64) return;              // wave 0 solves; no barriers after
  const int l = t;

  if (bid < K_) {
    const int i = bid;
    double x0 = 0.0, x1 = 0.0, x2 = 0.0;
    {
      double rdi = rd_s[i];
      if ((i & 63) == l) {
        int sl = i >> 6;
        if (sl == 0) x0 = rdi; else if (sl == 1) x1 = rdi; else x2 = rdi;
      }
    }
    for (int r = i + 1; r < K_; ++r) {
      int rb = (r * (r + 1)) >> 1;
      double partial = 0.0;
      { int k = l;       if (k < r) partial += Ls[rb + k] * x0; }
      { int k = l + 64;  if (k < r) partial += Ls[rb + k] * x1; }
      { int k = l + 128; if (k < r) partial += Ls[rb + k] * x2; }
      #pragma unroll
      for (int mm = 32; mm > 0; mm >>= 1) partial += __shfl_xor(partial, mm);
      double val = -partial * rd_s[r];
      if ((r & 63) == l) {
        int sl = r >> 6;
        if (sl == 0) x0 = val; else if (sl == 1) x1 = val; else x2 = val;
      }
    }
    double s2p = x0 * x0 + x1 * x1 + x2 * x2;
    #pragma unroll
    for (int mm = 32; mm > 0; mm >>= 1) s2p += __shfl_xor(s2p, mm);
    if (l == 0) s2g[i] = s2p;
  } else {
    // forward: L y = m
    double y0 = 0.0, y1 = 0.0, y2 = 0.0;
    for (int r = 0; r < K_; ++r) {
      int rb = (r * (r + 1)) >> 1;
      double partial = 0.0;
      { int k = l;       if (k < r) partial += Ls[rb + k] * y0; }
      { int k = l + 64;  if (k < r) partial += Ls[rb + k] * y1; }
      { int k = l + 128; if (k < r) partial += Ls[rb + k] * y2; }
      #pragma unroll
      for (int mm = 32; mm > 0; mm >>= 1) partial += __shfl_xor(partial, mm);
      double val = (m_sh[r] - partial) * rd_s[r];
      if ((r & 63) == l) {
        int sl = r >> 6;
        if (sl == 0) y0 = val; else if (sl == 1) y1 = val; else y2 = val;
      }
      if (l == 0) ys[r] = val;
    }
    // backward: L^T z = y
    double z0 = 0.0, z1 = 0.0, z2 = 0.0;
    for (int r = K_ - 1; r >= 0; --r) {
      double partial = 0.0;
      { int k = l;       if (k > r && k < K_) partial += Ls[((k * (k + 1)) >> 1) + r] * z0; }
      { int k = l + 64;  if (k > r && k < K_) partial += Ls[((k * (k + 1)) >> 1) + r] * z1; }
      { int k = l + 128; if (k > r && k < K_) partial += Ls[((k * (k + 1)) >> 1) + r] * z2; }
      #pragma unroll
      for (int mm = 32; mm > 0; mm >>= 1) partial += __shfl_xor(partial, mm);
      double val = (ys[r] - partial) * rd_s[r];
      if ((r & 63) == l) {
        int sl = r >> 6;
        if (sl == 0) z0 = val; else if (sl == 1) z1 = val; else z2 = val;
      }
      if (l == 0) zg[r] = val;
    }
  }
}

// ---------------- finals: omega, invsq, normv ------------------------------
__global__ __launch_bounds__(256) void k_finals(
    const double* __restrict__ rr, const double* __restrict__ s2g,
    const double* __restrict__ zg, double* __restrict__ invsq,
    float* __restrict__ normv)
{
  __shared__ double tmps[K_];
  const int t = threadIdx.x;
  if (t < K_) {
    double dii = s2g[t];
    double q = 1.0 / dii;
    double sm_ = zg[t] / dii;
    double var = (q - sm_ * sm_ / (double)N_) / (double)(N_ - 1);
    double t1 = sqrt(var) + 1e-30;
    double om = t1 * t1;
    invsq[t] = 1.0 / sqrt(om);
    tmps[t] = rr[t * LD + t] / om;
  }
  __syncthreads();
  if (t < 64) {
    double s = 0.0;
    for (int i = t; i < K_; i += 64) s += tmps[i];
    #pragma unroll
    for (int off = 32; off > 0; off >>= 1) s += __shfl_down(s, off);
    if (t == 0) *normv = (float)s;
  }
}

// ---------------- CholQR helper (operates on shQ K_ x MSUB, shS MSUB x 17) -
__device__ __forceinline__ void cholqr(double* shQ, double* shS, int t)
{
  // S = Q^T Q
  if (t < MSUB * MSUB) {
    int a = t & (MSUB - 1), b = t >> 4;
    double s = 0.0;
    for (int r = 0; r < K_; ++r) s += shQ[r * MSUB + a] * shQ[r * MSUB + b];
    shS[b * 17 + a] = s;
  }
  __syncthreads();
  // Cholesky 16x16 (lower)
  for (int k = 0; k < MSUB; ++k) {
    if (t == 0) shS[k * 17 + k] = sqrt(shS[k * 17 + k]);
    __syncthreads();
    if (t > k && t < MSUB) shS[t * 17 + k] /= shS[k * 17 + k];
    __syncthreads();
    if (t < MSUB * MSUB) {
      int r = t & (MSUB - 1), c = t >> 4;
      if (c > k && r >= c) shS[r * 17 + c] -= shS[r * 17 + k] * shS[c * 17 + k];
    }
    __syncthreads();
  }
  // rows solve: Qnew L^T = Qold
  if (t < K_) {
    double q[MSUB];
    #pragma unroll
    for (int c = 0; c < MSUB; ++c) {
      double v = shQ[t * MSUB + c];
      for (int p = 0; p < c; ++p) v -= q[p] * shS[c * 17 + p];
      q[c] = v / shS[c * 17 + c];
    }
    #pragma unroll
    for (int c = 0; c < MSUB; ++c) shQ[t * MSUB + c] = q[c];
  }
  __syncthreads();
}

// ---------------- one-block subspace iteration, top-16 eigenpairs ----------
__global__ __launch_bounds__(512) void k_sub(
    const double* __restrict__ rr, const double* __restrict__ invsq,
    float* __restrict__ W1, float* __restrict__ W2)
{
  extern __shared__ double dsm[];
  double* shQ  = dsm;                 // 3056
  double* shZ  = shQ + 3056;          // 3056
  double* shS  = shZ + 3056;          // 272 (16*17)
  double* Ws   = shS + 272;           // 272
  double* inv_s= Ws + 272;            // 192
  double* ev   = inv_s + 192;         // 16
  double* cs_  = ev + 16;             // 8
  double* sn_  = cs_ + 8;             // 8
  int* ipp  = (int*)(sn_ + 8);        // 8
  int* iqq  = ipp + 8;                // 8
  int* perm = iqq + 8;                // 16
  float* tri = (float*)(perm + 16);   // 18336
  const int t = threadIdx.x;

  if (t < K_) inv_s[t] = invsq[t];
  __syncthreads();
  // stage G lower triangle (f32): G_ij = rr_ij * invsq_i * invsq_j
  for (int i = t >> 4; i < K_; i += 32) {
    int base = (i * (i + 1)) / 2;
    double di = inv_s[i];
    for (int j = t & 15; j <= i; j += 16)
      tri[base + j] = (float)(rr[i * LD + j] * di * inv_s[j]);
  }
  __syncthreads();

  // init Q = G[:, 0:16]
  for (int idx = t; idx < K_ * MSUB; idx += 512) {
    int i = idx >> 4, c = idx & 15;
    float g = (i >= c) ? tri[(i * (i + 1)) / 2 + c] : tri[(c * (c + 1)) / 2 + i];
    shQ[idx] = (double)g;
  }
  __syncthreads();

  cholqr(shQ, shS, t);
  for (int it = 0; it < 4; ++it) {
    // copy Q -> Z
    for (int idx = t; idx < K_ * MSUB; idx += 512) shZ[idx] = shQ[idx];
    __syncthreads();
    // Q = G * Z (triangular-packed G), 2 rows x 4 cols per thread.
    if (t < 96 * 4) {
      int i2 = t >> 2, c4 = t & 3;
      int r0 = 2 * i2, r1 = r0 + 1;
      int has1 = (r1 < K_);
      int rb0 = (r0 * (r0 + 1)) >> 1;
      int rb1 = has1 ? ((r1 * (r1 + 1)) >> 1) : rb0;
      int cb0 = c4 * 4;
      double s0a = 0.0, s0b = 0.0, s0c = 0.0, s0d = 0.0;
      double s1a = 0.0, s1b = 0.0, s1c = 0.0, s1d = 0.0;
      #pragma unroll 2
      for (int k = 0; k <= r0; ++k) {
        double g0 = (double)tri[rb0 + k];
        double g1 = (double)tri[rb1 + k];
        double za = shZ[k * MSUB + cb0],     zb = shZ[k * MSUB + cb0 + 1];
        double zc = shZ[k * MSUB + cb0 + 2], zd = shZ[k * MSUB + cb0 + 3];
        s0a += g0 * za; s0b += g0 * zb; s0c += g0 * zc; s0d += g0 * zd;
        s1a += g1 * za; s1b += g1 * zb; s1c += g1 * zc; s1d += g1 * zd;
      }
      if (has1) {
        double g0 = (double)tri[rb1 + r0];   // G[r0][r1] via symmetry
        double g1 = (double)tri[rb1 + r1];
        double za = shZ[r1 * MSUB + cb0],     zb = shZ[r1 * MSUB + cb0 + 1];
        double zc = shZ[r1 * MSUB + cb0 + 2], zd = shZ[r1 * MSUB + cb0 + 3];
        s0a += g0 * za; s0b += g0 * zb; s0c += g0 * zc; s0d += g0 * zd;
        s1a += g1 * za; s1b += g1 * zb; s1c += g1 * zc; s1d += g1 * zd;
      }
      int kk = ((r1 + 1) * (r1 + 2)) >> 1;
      #pragma unroll 2
      for (int k = r1 + 1; k < K_; ++k) {
        double g0 = (double)tri[kk + r0];
        double g1 = (double)tri[kk + r1];
        double za = shZ[k * MSUB + cb0],     zb = shZ[k * MSUB + cb0 + 1];
        double zc = shZ[k * MSUB + cb0 + 2], zd = shZ[k * MSUB + cb0 + 3];
        s0a += g0 * za; s0b += g0 * zb; s0c += g0 * zc; s0d += g0 * zd;
        s1a += g1 * za; s1b += g1 * zb; s1c += g1 * zc; s1d += g1 * zd;
        kk += k + 1;
      }
      shQ[r0 * MSUB + cb0]     = s0a;
      shQ[r0 * MSUB + cb0 + 1] = s0b;
      shQ[r0 * MSUB + cb0 + 2] = s0c;
      shQ[r0 * MSUB + cb0 + 3] = s0d;
      if (has1) {
        shQ[r1 * MSUB + cb0]     = s1a;
        shQ[r1 * MSUB + cb0 + 1] = s1b;
        shQ[r1 * MSUB + cb0 + 2] = s1c;
        shQ[r1 * MSUB + cb0 + 3] = s1d;
      }
    }
    __syncthreads();
    if (it < 3) cholqr(shQ, shS, t);
  }
  // here: shZ = Q_orth, shQ = G*Q_orth.  T = Z^T Q  -> shS
  if (t < MSUB * MSUB) {
    int a = t & 15, b = t >> 4;
    double s = 0.0;
    for (int r = 0; r < K_; ++r) s += shZ[r * MSUB + b] * shQ[r * MSUB + a];
    shS[b * 17 + a] = s;
  }
  // init Ws = I
  if (t < MSUB * 17) Ws[t] = 0.0;
  __syncthreads();
  if (t < MSUB) Ws[t * 17 + t] = 1.0;
  __syncthreads();
  // Jacobi eigensolve of 16x16 T
  for (int sweep = 0; sweep < 6; ++sweep) {
    for (int round = 0; round < 15; ++round) {
      if (t < 8) {
        int ia = (t == 0) ? 0 : (1 + ((t - 1 + round) % 15));
        int ib = 1 + ((14 - t + round) % 15);
        int p = ia < ib ? ia : ib;
        int q = ia < ib ? ib : ia;
        double app = shS[p * 17 + p], aqq = shS[q * 17 + q], apq = shS[p * 17 + q];
        double c = 1.0, s = 0.0;
        if (fabs(apq) > 1e-30 * (fabs(app) + fabs(aqq)) && apq != 0.0) {
          double tau = (aqq - app) / (2.0 * apq);
          double tt = (tau >= 0.0 ? 1.0 : -1.0) / (fabs(tau) + sqrt(1.0 + tau * tau));
          c = 1.0 / sqrt(1.0 + tt * tt); s = tt * c;
        }
        cs_[t] = c; sn_[t] = s; ipp[t] = p; iqq[t] = q;
      }
      __syncthreads();
      if (t < 128) {   // column rotations of T and Ws
        int i = t & 15, mI = t >> 4;
        int p = ipp[mI], q = iqq[mI];
        double c = cs_[mI], s = sn_[mI];
        double u = shS[i * 17 + p], v = shS[i * 17 + q];
        shS[i * 17 + p] = c * u - s * v; shS[i * 17 + q] = s * u + c * v;
        double wu = Ws[i * 17 + p], wv = Ws[i * 17 + q];
        Ws[i * 17 + p] = c * wu - s * wv; Ws[i * 17 + q] = s * wu + c * wv;
      }
      __syncthreads();
      if (t < 128) {   // row rotations of T
        int j = t & 15, mI = t >> 4;
        int p = ipp[mI], q = iqq[mI];
        double c = cs_[mI], s = sn_[mI];
        double u = shS[p * 17 + j], v = shS[q * 17 + j];
        shS[p * 17 + j] = c * u - s * v; shS[q * 17 + j] = s * u + c * v;
      }
      __syncthreads();
    }
  }
  if (t == 0) {
    for (int i = 0; i < MSUB; ++i) { ev[i] = shS[i * 17 + i]; perm[i] = i; }
    for (int i = 0; i < MSUB; ++i) {
      int best = i;
      for (int j = i + 1; j < MSUB; ++j)
        if (ev[perm[j]] > ev[perm[best]]) best = j;
      int tp = perm[i]; perm[i] = perm[best]; perm[best] = tp;
    }
  }
  __syncthreads();
  // E = Q_orth * Ws (sorted); W1[i][c] = invsq_i * E ; W2[c][i] = E * sqrt(om_i)
  for (int idx = t; idx < K_ * MSUB; idx += 512) {
    int i = idx >> 4, c = idx & 15;
    int pc_ = perm[c];
    double e = 0.0;
    #pragma unroll
    for (int p = 0; p < MSUB; ++p) e += shZ[i * MSUB + p] * Ws[p * 17 + pc_];
    W1[i * MSUB + c] = (float)(inv_s[i] * e);
    W2[c * K_ + i]   = (float)(e / inv_s[i]);
  }
}

// ---------------- pc = x * W1 (f32), channel-major output ------------------
__global__ __launch_bounds__(256) void k_pc(const float* __restrict__ x,
                                            const float* __restrict__ W1,
                                            float* __restrict__ pc)
{
  __shared__ float xs[32][192];
  __shared__ float w1s[K_ * MSUB];
  int t = threadIdx.x;
  long n0 = (long)blockIdx.x * 32;
  for (int idx = t; idx < K_ * MSUB; idx += 256) w1s[idx] = W1[idx];
  for (int idx = t; idx < 32 * K_; idx += 256) {
    int row = idx / K_, col = idx - row * K_;
    xs[row][col] = x[(n0 + row) * K_ + col];
  }
  __syncthreads();
  int c = t & 15, nl = t >> 4;         // nl in [0,16)
  float a0 = 0.f, a1 = 0.f;
  for (int k = 0; k < K_; ++k) {
    float w = w1s[k * MSUB + c];
    a0 += xs[nl][k] * w;
    a1 += xs[nl + 16][k] * w;
  }
  __syncthreads();
  float* ts = &xs[0][0];               // reuse as 16x33 transpose buffer
  ts[c * 33 + nl]      = a0;
  ts[c * 33 + nl + 16] = a1;
  __syncthreads();
  for (int idx = t; idx < MSUB * 32; idx += 256) {
    int cc = idx >> 5, nn = idx & 31;
    pc[(size_t)cc * N_ + n0 + nn] = ts[cc * 33 + nn];
  }
}

// ---------------- DWT: vertical analysis pass ------------------------------
__global__ __launch_bounds__(256) void k_dwtv(const float* __restrict__ in,
                                              float* __restrict__ outv, int s)
{
  long gid = (long)blockIdx.x * 256 + threadIdx.x;
  int h = s >> 1;
  long per = (long)h * s;
  if (gid >= MSUB * per) return;
  int ch = (int)(gid / per);
  long rem = gid - (long)ch * per;
  int r = (int)(rem / s);
  int col = (int)(rem - (long)r * s);
  const float* cin = in + (long)ch * s * s;
  float la = 0.f, ld_ = 0.f;
  int base = 2 * r;
  #pragma unroll
  for (int l = 0; l < 10; ++l) {
    int rr_ = base + l; if (rr_ >= s) rr_ -= s;
    float v = cin[(long)rr_ * s + col];
    la += c_lo[l] * v; ld_ += c_hi[l] * v;
  }
  float* cout = outv + (long)ch * s * s;
  cout[(long)r * s + col] = la;
  cout[(long)(h + r) * s + col] = ld_;
}

// ---------------- DWT: horizontal analysis pass ----------------------------
__global__ __launch_bounds__(256) void k_dwth(const float* __restrict__ inv,
                                              float* __restrict__ llout,
                                              float* __restrict__ coef,
                                              int s, long offL, int last)
{
  long gid = (long)blockIdx.x * 256 + threadIdx.x;
  int h = s >> 1;
  long per = (long)s * h;
  if (gid >= MSUB * per) return;
  int ch = (int)(gid / per);
  long rem = gid - (long)ch * per;
  int r = (int)(rem / h);
  int mcol = (int)(rem - (long)r * h);
  const float* row = inv + (long)ch * s * s + (long)r * s;
  float lo = 0.f, hi = 0.f;
  int base = 2 * mcol;
  #pragma unroll
  for (int l = 0; l < 10; ++l) {
    int cc = base + l; if (cc >= s) cc -= s;
    float v = row[cc];
    lo += c_lo[l] * v; hi += c_hi[l] * v;
  }
  float* cslab = coef + (size_t)ch * N_ + offL;
  if (r < h) {
    llout[(size_t)ch * h * h + (long)r * h + mcol] = lo;
    if (last) coef[(size_t)ch * N_ + 147312 + (long)r * h + mcol] = lo;
    cslab[(long)r * h + mcol] = hi;
  } else {
    int rd = r - h;
    cslab[(long)h * h + (long)rd * h + mcol] = lo;
    cslab[(long)2 * h * h + (long)rd * h + mcol] = hi;
  }
}

// ---------------- SURE statistics per channel ------------------------------
__global__ __launch_bounds__(256) void k_stats(const float* __restrict__ coef,
                                               float* __restrict__ stats)
{
  int ch = blockIdx.x;
  int t = threadIdx.x;
  float T2[NT];
  {
    double stop = sqrt(log(147456.0));
    double step = stop / 14.0;
    for (int i = 0; i < NT; ++i) {
      double td = (i == 14) ? stop : (double)i * step;
      float tf = (float)td;
      T2[i] = tf * tf;
    }
  }
  float cn = 0.f, sm[NT], ct[NT];
  #pragma unroll
  for (int i = 0; i < NT; ++i) { sm[i] = 0.f; ct[i] = 0.f; }
  const float* base = coef + (size_t)ch * N_;
  for (int idx = t; idx < N_; idx += 256) {
    float v = base[idx];
    float v2 = v * v;
    cn += v2;
    #pragma unroll
    for (int i = 0; i < NT; ++i) {
      sm[i] += fminf(v2, T2[i]);
      ct[i] += (v2 > T2[i]) ? 1.0f : 0.0f;
    }
  }
  // in-wave shfl reduction (1 barrier total)
  __shared__ float red2[4][32];
  int lane = t & 63, wv = t >> 6;
  for (int a = 0; a < 31; ++a) {
    float val = (a == 0) ? cn : ((a < 16) ? sm[a - 1] : ct[a - 16]);
    #pragma unroll
    for (int off = 32; off > 0; off >>= 1) val += __shfl_down(val, off);
    if (lane == 0) red2[wv][a] = val;
  }
  __syncthreads();
  if (t < 31)
    stats[ch * 31 + t] = red2[0][t] + red2[1][t] + red2[2][t] + red2[3][t];
}

// ---------------- SURE scan + rank -----------------------------------------
__global__ void k_rank(const float* __restrict__ stats,
                       const float* __restrict__ normv, int* __restrict__ rankp)
{
  if (threadIdx.x != 0 || blockIdx.x != 0) return;
  float c_const = *normv - 28164096.0f;
  float acc[NT];
  for (int i = 0; i < NT; ++i) acc[i] = 0.f;
  float minsure[MSUB];
  for (int r = 0; r < MSUB; ++r) {
    float cn = stats[r * 31 + 0];
    float mn = 3.4e38f;
    for (int i = 0; i < NT; ++i) {
      float sure = stats[r * 31 + 1 + i] + 2.0f * stats[r * 31 + 16 + i] - cn;
      float s_r = acc[i] + sure + c_const;
      acc[i] = acc[i] + s_r;
      if (s_r < mn) mn = s_r;
    }
    minsure[r] = mn;
  }
  int rank = -1;
  for (int r = 2; r < MSUB; ++r) {
    if (minsure[r] > minsure[r - 1]) { rank = r; break; }
  }
  if (rank < 0) rank = MSUB - 1;
  *rankp = rank;
}

// ---------------- output: out = sqrt(omega) .* (pc[:, :rank] @ vh) ---------
__global__ __launch_bounds__(256) void k_out(const float* __restrict__ pc,
                                             const float* __restrict__ W2,
                                             const int* __restrict__ rankp,
                                             float* __restrict__ out)
{
  long gid = (long)blockIdx.x * 256 + threadIdx.x;
  int n = (int)(gid / K_);
  int j = (int)(gid - (long)n * K_);
  int rank = *rankp;
  float acc = 0.f;
  for (int c = 0; c < rank; ++c)
    acc += pc[(size_t)c * N_ + n] * W2[c * K_ + j];
  out[gid] = acc;
}

extern "C" void kernel_launch(void* const* d_in, const int* in_sizes, int n_in,
                              void* d_out, int out_size, void* d_ws, size_t ws_size,
                              hipStream_t stream)
{
  if (n_in < 1 || in_sizes[0] != N_ * K_) return;
  const float* x = (const float*)d_in[0];
  float* out = (float*)d_out;
  (void)out_size;

  char* w = (char*)d_ws;
  size_t off = 0;
  auto alloc = [&](size_t bytes) -> char* {
    char* p = w + off;
    off = (off + bytes + 255) & ~(size_t)255;
    return p;
  };
  double* m_    = (double*)alloc(K_ * 8);
  double* rrp   = (double*)alloc((size_t)K_ * K_ * 8);   // atomically-accumulated Gram
  double* rr    = (double*)alloc((size_t)K_ * LD * 8);
  double* Lg    = (double*)alloc((size_t)TRI_N * 8);
  double* rdg   = (double*)alloc(192 * 8);
  double* s2g   = (double*)alloc(192 * 8);
  double* zg    = (double*)alloc(192 * 8);
  double* invsq = (double*)alloc(K_ * 8);
  float*  normv = (float*)alloc(256);
  float*  W1    = (float*)alloc((size_t)K_ * MSUB * 4);
  float*  W2    = (float*)alloc((size_t)MSUB * K_ * 4);
  float*  pc    = (float*)alloc((size_t)MSUB * N_ * 4);
  float*  tmpv  = (float*)alloc((size_t)MSUB * N_ * 4);
  float*  coef  = (float*)alloc((size_t)MSUB * N_ * 4);
  float*  curA  = (float*)alloc((size_t)MSUB * 192 * 192 * 4);
  float*  curB  = (float*)alloc((size_t)MSUB * 96 * 96 * 4);
  float*  stats = (float*)alloc((size_t)MSUB * 31 * 4);
  int*    rankp = (int*)alloc(256);
  if (off > ws_size) return;

  hipMemsetAsync(m_, 0, K_ * sizeof(double), stream);
  hipMemsetAsync(rrp, 0, (size_t)K_ * K_ * sizeof(double), stream);

  hipFuncSetAttribute(reinterpret_cast<const void*>(k_chol),
                      hipFuncAttributeMaxDynamicSharedMemorySize, SMEM_CHOL);
  hipFuncSetAttribute(reinterpret_cast<const void*>(k_csolve),
                      hipFuncAttributeMaxDynamicSharedMemorySize, SMEM_SOLVE);
  hipFuncSetAttribute(reinterpret_cast<const void*>(k_sub),
                      hipFuncAttributeMaxDynamicSharedMemorySize, SMEM2_SZ);

  k_rr<<<NPAIR * NSPLIT, 256, 0, stream>>>(x, rrp, m_);
  k_reduce<<<(TRI_N + 255) / 256, 256, 0, stream>>>(rrp, rr);
  k_chol<<<1, 512, SMEM_CHOL, stream>>>(rr, Lg, rdg);
  k_csolve<<<K_ + 1, 256, SMEM_SOLVE, stream>>>(Lg, rdg, m_, s2g, zg);
  k_finals<<<1, 256, 0, stream>>>(rr, s2g, zg, invsq, normv);
  k_sub<<<1, 512, SMEM2_SZ, stream>>>(rr, invsq, W1, W2);
  k_pc<<<N_ / 32, 256, 0, stream>>>(x, W1, pc);

  int   sizes[5] = {384, 192, 96, 48, 24};
  long  offs[5]  = {0, 110592, 138240, 145152, 146880};
  float* lls[5]  = {curA, curB, curA, curB, curA};
  const float* curin = pc;
  for (int lev = 0; lev < 5; ++lev) {
    int s = sizes[lev], h = s >> 1;
    long nth = (long)MSUB * h * s;
    k_dwtv<<<(int)((nth + 255) / 256), 256, 0, stream>>>(curin, tmpv, s);
    k_dwth<<<(int)((nth + 255) / 256), 256, 0, stream>>>(tmpv, lls[lev], coef,
                                                         s, offs[lev],
                                                         lev == 4 ? 1 : 0);
    curin = lls[lev];
  }

  k_stats<<<MSUB, 256, 0, stream>>>(coef, stats);
  k_rank<<<1, 64, 0, stream>>>(stats, normv, rankp);
  k_out<<<(N_ * K_) / 256, 256, 0, stream>>>(pc, W2, rankp, out);
}